// Round 5
// baseline (233.922 us; speedup 1.0000x reference)
//
#include <hip/hip_runtime.h>
#include <hip/hip_bf16.h>
#include <math.h>

typedef float f32x4_t __attribute__((ext_vector_type(4)));
typedef float f32x2_t __attribute__((ext_vector_type(2)));
typedef __bf16 bf16x8_t __attribute__((ext_vector_type(8)));

__device__ __forceinline__ float bf2f(unsigned int u){
  union { float f; unsigned int i; } x; x.i = u << 16; return x.f;
}
__device__ __forceinline__ unsigned short f2bf(float f){
  unsigned int x = __float_as_uint(f);
  unsigned int r = (x + 0x7fffu + ((x >> 16) & 1u)) >> 16;
  return (unsigned short)r;
}
__device__ __forceinline__ unsigned int pk2bf(float a, float b){
  return (unsigned int)f2bf(a) | ((unsigned int)f2bf(b) << 16);
}
// LDS unit swizzle: r = LDS row (0..127), returns 2-bit XOR for 16B-unit index
__device__ __forceinline__ int swz4(int r){ return (r ^ (r >> 2) ^ (r >> 4)) & 3; }

// unpack 8 bf16 (uint4) -> 8 floats, scaled
__device__ __forceinline__ void unp8s(uint4 w, float* f, float s){
  f[0] = bf2f(w.x & 0xffffu) * s; f[1] = bf2f(w.x >> 16) * s;
  f[2] = bf2f(w.y & 0xffffu) * s; f[3] = bf2f(w.y >> 16) * s;
  f[4] = bf2f(w.z & 0xffffu) * s; f[5] = bf2f(w.z >> 16) * s;
  f[6] = bf2f(w.w & 0xffffu) * s; f[7] = bf2f(w.w >> 16) * s;
}
// unpack 4 fp8 e4m3 (one u32) -> 4 floats (HW cvt)
__device__ __forceinline__ void unpf8(unsigned int w, float* f){
  f32x2_t lo = __builtin_amdgcn_cvt_pk_f32_fp8(w, false);
  f32x2_t hi = __builtin_amdgcn_cvt_pk_f32_fp8(w, true);
  f[0] = lo[0]; f[1] = lo[1]; f[2] = hi[0]; f[3] = hi[1];
}

#define GLOAD16(gsrc, ldst) \
  __builtin_amdgcn_global_load_lds((const __attribute__((address_space(1))) unsigned int*)(gsrc), \
                                   (__attribute__((address_space(3))) unsigned int*)(ldst), 16, 0, 0)

// ---------------- K0: pack weights -> wcatT bf16 [1024][512] PRE-SWIZZLED, biases -> bcat f32[1024]
// wcatT holds the exact LDS image: slot (c, ktile, phys_unit p, k&7) stores logical unit p^swz4(c&127)
__global__ void pack_weights(const float* __restrict__ Wq, const float* __restrict__ Wk,
                             const float* __restrict__ Wv, const float* __restrict__ Ws,
                             const float* __restrict__ bq, const float* __restrict__ bk,
                             const float* __restrict__ bv, const float* __restrict__ bs,
                             unsigned short* __restrict__ wcatT, float* __restrict__ bcat){
  int idx = blockIdx.x * 256 + threadIdx.x;
  if (idx < 1024 * 512){
    int c = idx >> 9, k = idx & 511;
    int sel = c >> 8, cc = c & 255;
    const float* W = (sel == 0) ? Wq : (sel == 1) ? Wk : (sel == 2) ? Wv : Ws;
    int p = ((k >> 3) & 3) ^ swz4(c & 127);
    int dst = c * 512 + (k & ~31) + p * 8 + (k & 7);
    wcatT[dst] = f2bf(W[k * 256 + cc]);
  }
  if (idx < 1024){
    int sel = idx >> 8, cc = idx & 255;
    const float* B = (sel == 0) ? bq : (sel == 1) ? bk : (sel == 2) ? bv : bs;
    bcat[idx] = B[cc];
  }
}

// ---------------- K0b: pack Wa1^T -> bf16 [256 cols][256 k]
__global__ void pack_wa1(const float* __restrict__ Wa1, unsigned short* __restrict__ wa1T){
  int idx = blockIdx.x * 256 + threadIdx.x;  // 65536
  int c = idx >> 8, k = idx & 255;
  wa1T[idx] = f2bf(Wa1[k * 256 + c]);
}

// ---------------- K3: fused QKVS GEMM: reads x fp32, writes q/s bf16 + k/v fp8
// 128x128 tile, XCD swizzle, pipelined reg-staged A (swizzled LDS), pre-swizzled B via gload_lds,
// swapped-operand MFMA, chunked LDS-staged coalesced epilogue.
__global__ __launch_bounds__(256) void gemm_qkvs(const float* __restrict__ x,
                                                 const unsigned short* __restrict__ wcatT,
                                                 const float* __restrict__ bcat,
                                                 unsigned short* __restrict__ qbf,
                                                 unsigned short* __restrict__ sbf,
                                                 unsigned char* __restrict__ kv8,
                                                 int n_nodes, int mblocks){
  __shared__ __align__(16) unsigned char smem[17408];   // K-loop: As 8KB + Bs 8KB; epilogue chunk [64][136] bf16
  unsigned short* As = (unsigned short*)smem;            // [128][32] bf16, unit-swizzled
  unsigned short* Bs = (unsigned short*)(smem + 8192);   // [128][32] bf16, unit-swizzled (baked in wcatT)
  const int tid = threadIdx.x;
  const int lane = tid & 63, wave = tid >> 6;
  const int wm = wave >> 1, wn = wave & 1;
  const int g = (blockIdx.x & 7) * mblocks + (blockIdx.x >> 3);
  const int m_blk = g >> 3, n_blk = g & 7;
  const int m0 = m_blk * 128, n0 = n_blk * 128;
  // A staging: thread -> (row = tid>>1, logical units au0, au0+1)
  const int arow = tid >> 1;
  const int au0 = (tid & 1) * 2;
  const int ap0 = (au0 ^ swz4(arow)) * 8;
  const int ap1 = ((au0 + 1) ^ swz4(arow)) * 8;
  const float* aptr = x + (size_t)min(m0 + arow, n_nodes - 1) * 512 + au0 * 8;
  // B rows for global_load_lds (linear copy; swizzle pre-baked in wcatT)
  const int brow = n0 + wave * 16 + (lane >> 2);
  const int bcol = (lane & 3) * 8;
  const int r = lane & 15, q4 = lane >> 4;
  // hoisted swizzled fragment read offsets (shorts)
  int aoff[4], boff[4];
  #pragma unroll
  for (int mi = 0; mi < 4; mi++){ int rr = wm * 64 + mi * 16 + r; aoff[mi] = rr * 32 + ((q4 ^ swz4(rr)) * 8); }
  #pragma unroll
  for (int ni = 0; ni < 4; ni++){ int rb = wn * 64 + ni * 16 + r; boff[ni] = rb * 32 + ((q4 ^ swz4(rb)) * 8); }
  f32x4_t acc[4][4] = {};
  // prologue: prefetch A regs for k0=0
  float4 af0 = *reinterpret_cast<const float4*>(aptr);
  float4 af1 = *reinterpret_cast<const float4*>(aptr + 4);
  float4 af2 = *reinterpret_cast<const float4*>(aptr + 8);
  float4 af3 = *reinterpret_cast<const float4*>(aptr + 12);
  for (int k0 = 0; k0 < 512; k0 += 32){
    GLOAD16(wcatT + (size_t)brow * 512 + k0 + bcol, &Bs[wave * 512]);
    GLOAD16(wcatT + (size_t)(brow + 64) * 512 + k0 + bcol, &Bs[(wave + 4) * 512]);
    uint4 o0, o1;
    o0.x = pk2bf(af0.x, af0.y); o0.y = pk2bf(af0.z, af0.w);
    o0.z = pk2bf(af1.x, af1.y); o0.w = pk2bf(af1.z, af1.w);
    o1.x = pk2bf(af2.x, af2.y); o1.y = pk2bf(af2.z, af2.w);
    o1.z = pk2bf(af3.x, af3.y); o1.w = pk2bf(af3.z, af3.w);
    *reinterpret_cast<uint4*>(&As[arow * 32 + ap0]) = o0;
    *reinterpret_cast<uint4*>(&As[arow * 32 + ap1]) = o1;
    __syncthreads();
    if (k0 + 32 < 512){   // prefetch next A regs; latency hides under MFMA
      af0 = *reinterpret_cast<const float4*>(aptr + k0 + 32);
      af1 = *reinterpret_cast<const float4*>(aptr + k0 + 36);
      af2 = *reinterpret_cast<const float4*>(aptr + k0 + 40);
      af3 = *reinterpret_cast<const float4*>(aptr + k0 + 44);
    }
    bf16x8_t a[4], b[4];
    #pragma unroll
    for (int mi = 0; mi < 4; mi++) a[mi] = *reinterpret_cast<const bf16x8_t*>(&As[aoff[mi]]);
    #pragma unroll
    for (int ni = 0; ni < 4; ni++) b[ni] = *reinterpret_cast<const bf16x8_t*>(&Bs[boff[ni]]);
    #pragma unroll
    for (int mi = 0; mi < 4; mi++)
      #pragma unroll
      for (int ni = 0; ni < 4; ni++)
        acc[mi][ni] = __builtin_amdgcn_mfma_f32_16x16x32_bf16(b[ni], a[mi], acc[mi][ni], 0, 0, 0);
    __syncthreads();
  }
  // ---- epilogue: 2 chunks of 64 rows (by wm), LDS-staged, coalesced ----
  const bool isQ = (n_blk < 2), isS = (n_blk >= 6);
  if (isQ || isS){
    unsigned short* St = (unsigned short*)smem;   // [64][136] bf16
    unsigned short* outp = isQ ? qbf : sbf;
    const int colhalf = isQ ? n_blk : (n_blk - 6);
    #pragma unroll
    for (int ch = 0; ch < 2; ch++){
      if (wm == ch){
        #pragma unroll
        for (int mi = 0; mi < 4; mi++){
          #pragma unroll
          for (int ni = 0; ni < 4; ni++){
            int mloc = mi * 16 + r;
            int nl = wn * 64 + ni * 16 + q4 * 4;
            float4 bb = *reinterpret_cast<const float4*>(&bcat[n0 + nl]);
            uint2 w;
            w.x = pk2bf(acc[mi][ni][0] + bb.x, acc[mi][ni][1] + bb.y);
            w.y = pk2bf(acc[mi][ni][2] + bb.z, acc[mi][ni][3] + bb.w);
            *reinterpret_cast<uint2*>(&St[mloc * 136 + nl]) = w;
          }
        }
      }
      __syncthreads();
      #pragma unroll
      for (int it = 0; it < 4; it++){
        int u = it * 256 + tid;
        int row = u >> 4, seg = (u & 15) * 8;
        int node = m0 + ch * 64 + row;
        if (node < n_nodes){
          uint4 v = *reinterpret_cast<const uint4*>(&St[row * 136 + seg]);
          *reinterpret_cast<uint4*>(outp + (size_t)node * 256 + colhalf * 128 + seg) = v;
        }
      }
      __syncthreads();
    }
  } else {
    unsigned char* St8 = smem;                    // [64][144] fp8
    #pragma unroll
    for (int ch = 0; ch < 2; ch++){
      if (wm == ch){
        #pragma unroll
        for (int mi = 0; mi < 4; mi++){
          #pragma unroll
          for (int ni = 0; ni < 4; ni++){
            int mloc = mi * 16 + r;
            int nl = wn * 64 + ni * 16 + q4 * 4;
            float4 bb = *reinterpret_cast<const float4*>(&bcat[n0 + nl]);
            int u = 0;
            u = __builtin_amdgcn_cvt_pk_fp8_f32(acc[mi][ni][0] + bb.x, acc[mi][ni][1] + bb.y, u, false);
            u = __builtin_amdgcn_cvt_pk_fp8_f32(acc[mi][ni][2] + bb.z, acc[mi][ni][3] + bb.w, u, true);
            *reinterpret_cast<unsigned int*>(&St8[mloc * 144 + nl]) = (unsigned int)u;
          }
        }
      }
      __syncthreads();
      #pragma unroll
      for (int it = 0; it < 2; it++){
        int u = it * 256 + tid;
        int row = u >> 3, seg = (u & 7) * 16;
        int node = m0 + ch * 64 + row;
        if (node < n_nodes){
          uint4 v = *reinterpret_cast<const uint4*>(&St8[row * 144 + seg]);
          *reinterpret_cast<uint4*>(kv8 + (size_t)node * 512 + (n_blk - 2) * 128 + seg) = v;
        }
      }
      __syncthreads();
    }
  }
}

// ---------------- K4: degree histogram
__global__ void degree_hist(const int* __restrict__ ei, int* __restrict__ deg, int ne){
  int i = blockIdx.x * 256 + threadIdx.x;
  if (i < ne) atomicAdd(&deg[ei[ne + i]], 1);
}

// ---------------- K5: exclusive scan, single block, 2-pass blocked
__global__ void scan_deg(const int* __restrict__ deg, int* __restrict__ rowstart, int n, int ne){
  __shared__ int sm[1024];
  int tid = threadIdx.x;
  int per = (n + 1023) / 1024;
  int start = tid * per;
  int sum = 0;
  for (int i = 0; i < per; i++){
    int idx = start + i;
    sum += (idx < n) ? deg[idx] : 0;
  }
  sm[tid] = sum; __syncthreads();
  for (int off = 1; off < 1024; off <<= 1){
    int t = (tid >= off) ? sm[tid - off] : 0;
    __syncthreads();
    sm[tid] += t;
    __syncthreads();
  }
  int run = sm[tid] - sum;
  for (int i = 0; i < per; i++){
    int idx = start + i;
    if (idx < n){
      rowstart[idx] = run;
      run += deg[idx];
    }
  }
  if (tid == 0) rowstart[n] = ne;
}

// ---------------- K6: scatter edges into CSR (stores src*512 byte-offset)
__global__ void scatter_edges(const int* __restrict__ ei, const int* __restrict__ rowstart,
                              int* __restrict__ cursor, int* __restrict__ csrsrc, int ne){
  int i = blockIdx.x * 256 + threadIdx.x;
  if (i < ne){
    int d = ei[ne + i];
    int pos = atomicAdd(&cursor[d], 1);
    csrsrc[rowstart[d] + pos] = ei[i] << 9;
  }
}

// ---------------- K7: per-dst online-softmax aggregation (fp8 K/V, 16 lanes/edge, 4 nodes/wave)
__global__ __launch_bounds__(256) void edge_attn(const unsigned short* __restrict__ qbf,
                                                 const unsigned short* __restrict__ sbf,
                                                 const unsigned char* __restrict__ kv8,
                                                 const int* __restrict__ rowstart,
                                                 const int* __restrict__ csrsrc,
                                                 unsigned short* __restrict__ hbf, int n_nodes){
  const int tid = threadIdx.x;
  const int lane = tid & 63, wave = tid >> 6;
  const int g = lane >> 4, t = lane & 15;
  const int node = blockIdx.x * 16 + wave * 4 + g;
  const bool active = node < n_nodes;
  const int nd = active ? node : 0;
  const float qs = 0.0625f * 1.44269504088896340736f;  // (1/sqrt(256)) * log2(e)
  float q[16];
  {
    const unsigned short* qp = qbf + (size_t)nd * 256 + t * 16;
    uint4 w0 = *reinterpret_cast<const uint4*>(qp);
    uint4 w1 = *reinterpret_cast<const uint4*>(qp + 8);
    unp8s(w0, q, qs); unp8s(w1, q + 8, qs);
  }
  int rs = rowstart[nd];
  int re = active ? rowstart[nd + 1] : rs;
  float m = -1e30f, den = 0.f;
  float acc[16];
  #pragma unroll
  for (int j = 0; j < 16; j++) acc[j] = 0.f;
  for (int i = rs; i < re; i++){
    int soff = csrsrc[i];
    const unsigned char* kb = kv8 + (size_t)soff + t * 16;
    uint4 kw = *reinterpret_cast<const uint4*>(kb);
    float kf[16];
    unpf8(kw.x, kf); unpf8(kw.y, kf + 4); unpf8(kw.z, kf + 8); unpf8(kw.w, kf + 12);
    float s = 0.f;
    #pragma unroll
    for (int j = 0; j < 16; j++) s = fmaf(q[j], kf[j], s);
    s += __shfl_xor(s, 1); s += __shfl_xor(s, 2);
    s += __shfl_xor(s, 4); s += __shfl_xor(s, 8);
    uint4 vw = *reinterpret_cast<const uint4*>(kb + 256);
    float vf[16];
    unpf8(vw.x, vf); unpf8(vw.y, vf + 4); unpf8(vw.z, vf + 8); unpf8(vw.w, vf + 12);
    if (s > m){
      float sc = exp2f(m - s);
      den = den * sc + 1.0f;
      #pragma unroll
      for (int j = 0; j < 16; j++) acc[j] = fmaf(acc[j], sc, vf[j]);
      m = s;
    } else {
      float e = exp2f(s - m);
      den += e;
      #pragma unroll
      for (int j = 0; j < 16; j++) acc[j] = fmaf(e, vf[j], acc[j]);
    }
  }
  float inv = (den > 0.f) ? 1.f / den : 0.f;
  const unsigned short* sp = sbf + (size_t)nd * 256 + t * 16;
  uint4 s0 = *reinterpret_cast<const uint4*>(sp);
  uint4 s1 = *reinterpret_cast<const uint4*>(sp + 8);
  float sf[16]; unp8s(s0, sf, 1.0f); unp8s(s1, sf + 8, 1.0f);
  const float inv_sqrt2 = 0.70710678118654752f;
  unsigned int o[8];
  #pragma unroll
  for (int j = 0; j < 8; j++){
    float h0 = acc[2 * j] * inv + sf[2 * j];
    float h1 = acc[2 * j + 1] * inv + sf[2 * j + 1];
    h0 = 0.5f * h0 * (1.f + erff(h0 * inv_sqrt2));
    h1 = 0.5f * h1 * (1.f + erff(h1 * inv_sqrt2));
    o[j] = (unsigned int)f2bf(h0) | ((unsigned int)f2bf(h1) << 16);
  }
  if (active){
    uint4* dst = reinterpret_cast<uint4*>(hbf + (size_t)node * 256 + t * 16);
    dst[0] = make_uint4(o[0], o[1], o[2], o[3]);
    dst[1] = make_uint4(o[4], o[5], o[6], o[7]);
  }
}

// ---------------- K8: s2[n][2] = tanh(hbf@Wa1 + ba1)@Wa2 + ba2  (bf16 MFMA)
__global__ __launch_bounds__(256) void mlp_mfma(const unsigned short* __restrict__ hbf,
                                                const unsigned short* __restrict__ wa1T,
                                                const float* __restrict__ ba1,
                                                const float* __restrict__ Wa2,
                                                const float* __restrict__ ba2,
                                                float* __restrict__ s2, int n_nodes){
  __shared__ __align__(16) unsigned short As[64 * 72];
  __shared__ float s2s[64][2];
  const int tid = threadIdx.x;
  const int lane = tid & 63, wave = tid >> 6;
  const int m0 = blockIdx.x * 64;
  const int c0 = wave * 64;
  const int r = lane & 15, rg = (lane >> 4) * 4;
  if (tid < 128) s2s[tid >> 1][tid & 1] = 0.f;
  f32x4_t acc[4][4] = {};
  for (int k0 = 0; k0 < 256; k0 += 64){
    int arow = tid >> 2, akc = (tid & 3) * 16;
    uint4 a0v = make_uint4(0,0,0,0), a1v = make_uint4(0,0,0,0);
    if (m0 + arow < n_nodes){
      const unsigned short* src = hbf + (size_t)(m0 + arow) * 256 + k0 + akc;
      a0v = *reinterpret_cast<const uint4*>(src);
      a1v = *reinterpret_cast<const uint4*>(src + 8);
    }
    *reinterpret_cast<uint4*>(&As[arow * 72 + akc]) = a0v;
    *reinterpret_cast<uint4*>(&As[arow * 72 + akc + 8]) = a1v;
    __syncthreads();
    #pragma unroll
    for (int kk = 0; kk < 2; kk++){
      int kg = kk * 32 + (lane >> 4) * 8;
      bf16x8_t a[4], b[4];
      #pragma unroll
      for (int mi = 0; mi < 4; mi++)
        a[mi] = *reinterpret_cast<const bf16x8_t*>(&As[(mi * 16 + r) * 72 + kg]);
      #pragma unroll
      for (int ni = 0; ni < 4; ni++)
        b[ni] = *reinterpret_cast<const bf16x8_t*>(wa1T + (size_t)(c0 + ni * 16 + r) * 256 + k0 + kg);
      #pragma unroll
      for (int mi = 0; mi < 4; mi++)
        #pragma unroll
        for (int ni = 0; ni < 4; ni++)
          acc[mi][ni] = __builtin_amdgcn_mfma_f32_16x16x32_bf16(a[mi], b[ni], acc[mi][ni], 0, 0, 0);
    }
    __syncthreads();
  }
  float w20[4], w21[4], b1c[4];
  #pragma unroll
  for (int ni = 0; ni < 4; ni++){
    int col = c0 + ni * 16 + r;
    w20[ni] = Wa2[col * 2]; w21[ni] = Wa2[col * 2 + 1]; b1c[ni] = ba1[col];
  }
  #pragma unroll
  for (int mi = 0; mi < 4; mi++){
    #pragma unroll
    for (int j = 0; j < 4; j++){
      float t0 = 0.f, t1 = 0.f;
      #pragma unroll
      for (int ni = 0; ni < 4; ni++){
        float t = tanhf(acc[mi][ni][j] + b1c[ni]);
        t0 += t * w20[ni]; t1 += t * w21[ni];
      }
      t0 += __shfl_xor(t0, 1); t0 += __shfl_xor(t0, 2);
      t0 += __shfl_xor(t0, 4); t0 += __shfl_xor(t0, 8);
      t1 += __shfl_xor(t1, 1); t1 += __shfl_xor(t1, 2);
      t1 += __shfl_xor(t1, 4); t1 += __shfl_xor(t1, 8);
      if (r == 0){
        int row = mi * 16 + rg + j;
        atomicAdd(&s2s[row][0], t0);
        atomicAdd(&s2s[row][1], t1);
      }
    }
  }
  __syncthreads();
  if (tid < 128){
    int row = tid >> 1, c = tid & 1;
    int node = m0 + row;
    if (node < n_nodes) s2[node * 2 + c] = s2s[row][c] + ba2[c];
  }
}

// ---------------- K9: column max + exp-sum over n (single block)
__global__ void col_reduce(const float* __restrict__ s2, float* __restrict__ red, int n){
  __shared__ float sm[1024];
  __shared__ float mshare[2];
  int tid = threadIdx.x;
  float mx0 = -INFINITY, mx1 = -INFINITY;
  for (int i = tid; i < n; i += 1024){
    mx0 = fmaxf(mx0, s2[2 * i]);
    mx1 = fmaxf(mx1, s2[2 * i + 1]);
  }
  sm[tid] = mx0; __syncthreads();
  for (int off = 512; off > 0; off >>= 1){
    if (tid < off) sm[tid] = fmaxf(sm[tid], sm[tid + off]);
    __syncthreads();
  }
  if (tid == 0) mshare[0] = sm[0];
  __syncthreads();
  sm[tid] = mx1; __syncthreads();
  for (int off = 512; off > 0; off >>= 1){
    if (tid < off) sm[tid] = fmaxf(sm[tid], sm[tid + off]);
    __syncthreads();
  }
  if (tid == 0) mshare[1] = sm[0];
  __syncthreads();
  float m0 = mshare[0], m1 = mshare[1];
  float s0 = 0.f, s1 = 0.f;
  for (int i = tid; i < n; i += 1024){
    s0 += expf(s2[2 * i] - m0);
    s1 += expf(s2[2 * i + 1] - m1);
  }
  sm[tid] = s0; __syncthreads();
  for (int off = 512; off > 0; off >>= 1){
    if (tid < off) sm[tid] += sm[tid + off];
    __syncthreads();
  }
  float den0 = sm[0];
  __syncthreads();
  sm[tid] = s1; __syncthreads();
  for (int off = 512; off > 0; off >>= 1){
    if (tid < off) sm[tid] += sm[tid + off];
    __syncthreads();
  }
  if (tid == 0){
    red[0] = m0; red[1] = m1; red[2] = den0; red[3] = sm[0];
  }
}

// ---------------- K10: attn, A output, M partial accumulation (reads bf16 h)
__global__ __launch_bounds__(256) void attn_M(const float* __restrict__ s2, const float* __restrict__ red,
                                              const unsigned short* __restrict__ hbf, const int* __restrict__ label,
                                              float* __restrict__ Mbuf, float* __restrict__ outA, int n){
  __shared__ float a0s[256], a1s[256];
  int tid = threadIdx.x;
  int n0 = blockIdx.x * 256;
  int node = n0 + tid;
  float m0 = red[0], m1 = red[1];
  float i0 = 1.f / red[2], i1 = 1.f / red[3];
  float a0 = 0.f, a1 = 0.f;
  if (node < n){
    a0 = expf(s2[2 * node] - m0) * i0;
    a1 = expf(s2[2 * node + 1] - m1) * i1;
    outA[node] = (label[0] == 0) ? a0 : a1;
  }
  a0s[tid] = a0; a1s[tid] = a1;
  __syncthreads();
  int d = tid;
  float M0 = 0.f, M1 = 0.f;
  int cnt = min(256, n - n0);
  for (int i = 0; i < cnt; i++){
    float hv = bf2f((unsigned int)hbf[(size_t)(n0 + i) * 256 + d]);
    M0 += a0s[i] * hv;
    M1 += a1s[i] * hv;
  }
  atomicAdd(&Mbuf[d], M0);
  atomicAdd(&Mbuf[256 + d], M1);
}

// ---------------- K11: logits + Y_prob
__global__ void final_k(const float* __restrict__ Mbuf, const float* __restrict__ Wc,
                        const float* __restrict__ bc, float* __restrict__ out){
  __shared__ float sm[256];
  __shared__ float l0s;
  int tid = threadIdx.x;
  float p0 = Mbuf[tid] * Wc[tid];
  float p1 = Mbuf[256 + tid] * Wc[256 + tid];
  sm[tid] = p0; __syncthreads();
  for (int off = 128; off > 0; off >>= 1){
    if (tid < off) sm[tid] += sm[tid + off];
    __syncthreads();
  }
  if (tid == 0) l0s = sm[0];
  __syncthreads();
  sm[tid] = p1; __syncthreads();
  for (int off = 128; off > 0; off >>= 1){
    if (tid < off) sm[tid] += sm[tid + off];
    __syncthreads();
  }
  if (tid == 0){
    float l0 = l0s + bc[0];
    float l1 = sm[0] + bc[1];
    out[0] = l0; out[1] = l1;
    float mx = fmaxf(l0, l1);
    float e0 = expf(l0 - mx), e1 = expf(l1 - mx);
    float inv = 1.f / (e0 + e1);
    out[2] = e0 * inv; out[3] = e1 * inv;
  }
}

extern "C" void kernel_launch(void* const* d_in, const int* in_sizes, int n_in,
                              void* d_out, int out_size, void* d_ws, size_t ws_size,
                              hipStream_t stream) {
  const float* x   = (const float*)d_in[0];
  const int*   ei  = (const int*)d_in[1];
  const int*   lab = (const int*)d_in[2];
  const float* Wq  = (const float*)d_in[3];
  const float* bq  = (const float*)d_in[4];
  const float* Wk  = (const float*)d_in[5];
  const float* bk  = (const float*)d_in[6];
  const float* Wv  = (const float*)d_in[7];
  const float* bv  = (const float*)d_in[8];
  const float* Ws  = (const float*)d_in[9];
  const float* bs  = (const float*)d_in[10];
  const float* Wa1 = (const float*)d_in[11];
  const float* ba1 = (const float*)d_in[12];
  const float* Wa2 = (const float*)d_in[13];
  const float* ba2 = (const float*)d_in[14];
  const float* Wc  = (const float*)d_in[15];
  const float* bc  = (const float*)d_in[16];
  float* out = (float*)d_out;

  const int n  = in_sizes[0] / 512;   // 20000
  const int ne = in_sizes[1] / 2;     // 320000

  char* ws = (char*)d_ws;
  size_t off = 0;
  auto take = [&](size_t bytes){ size_t r = off; off += (bytes + 255) & ~(size_t)255; return r; };
  unsigned short* wcatT  = (unsigned short*)(ws + take((size_t)1024 * 512 * 2));
  float*          bcat   = (float*)(ws + take(1024 * 4));
  unsigned short* qbf    = (unsigned short*)(ws + take((size_t)n * 256 * 2));
  unsigned short* sbf    = (unsigned short*)(ws + take((size_t)n * 256 * 2));
  unsigned char*  kv8    = (unsigned char*)(ws + take((size_t)n * 512));
  unsigned short* hbf    = (unsigned short*)(ws + take((size_t)n * 256 * 2));
  unsigned short* wa1T   = (unsigned short*)(ws + take((size_t)256 * 256 * 2));
  float*          s2     = (float*)(ws + take((size_t)n * 2 * 4));
  size_t zoff = off;
  int*            deg    = (int*)(ws + take((size_t)n * 4));
  int*            cursor = (int*)(ws + take((size_t)n * 4));
  float*          Mbuf   = (float*)(ws + take(512 * 4));
  size_t zlen = off - zoff;
  int*            rowst  = (int*)(ws + take((size_t)(n + 1) * 4));
  int*            csrsrc = (int*)(ws + take((size_t)ne * 4));
  float*          red    = (float*)(ws + take(4 * 4));

  hipMemsetAsync(ws + zoff, 0, zlen, stream);

  pack_weights<<<(1024 * 512 + 255) / 256, 256, 0, stream>>>(Wq, Wk, Wv, Ws, bq, bk, bv, bs, wcatT, bcat);
  pack_wa1<<<256, 256, 0, stream>>>(Wa1, wa1T);
  const int mblocks = (n + 127) / 128;
  gemm_qkvs<<<8 * mblocks, 256, 0, stream>>>(x, wcatT, bcat, qbf, sbf, kv8, n, mblocks);
  degree_hist<<<(ne + 255) / 256, 256, 0, stream>>>(ei, deg, ne);
  scan_deg<<<1, 1024, 0, stream>>>(deg, rowst, n, ne);
  scatter_edges<<<(ne + 255) / 256, 256, 0, stream>>>(ei, rowst, cursor, csrsrc, ne);
  edge_attn<<<(n + 15) / 16, 256, 0, stream>>>(qbf, sbf, kv8, rowst, csrsrc, hbf, n);
  mlp_mfma<<<(n + 63) / 64, 256, 0, stream>>>(hbf, wa1T, ba1, Wa2, ba2, s2, n);
  col_reduce<<<1, 1024, 0, stream>>>(s2, red, n);
  attn_M<<<(n + 255) / 256, 256, 0, stream>>>(s2, red, hbf, lab, Mbuf, out + 4, n);
  final_k<<<1, 256, 0, stream>>>(Mbuf, Wc, bc, out);
  (void)ws_size; (void)out_size; (void)n_in;
}

// Round 6
// 227.074 us; speedup vs baseline: 1.0302x; 1.0302x over previous
//
#include <hip/hip_runtime.h>
#include <hip/hip_bf16.h>
#include <math.h>

typedef float f32x4_t __attribute__((ext_vector_type(4)));
typedef float f32x2_t __attribute__((ext_vector_type(2)));
typedef __bf16 bf16x8_t __attribute__((ext_vector_type(8)));

__device__ __forceinline__ float bf2f(unsigned int u){
  union { float f; unsigned int i; } x; x.i = u << 16; return x.f;
}
__device__ __forceinline__ unsigned short f2bf(float f){
  unsigned int x = __float_as_uint(f);
  unsigned int r = (x + 0x7fffu + ((x >> 16) & 1u)) >> 16;
  return (unsigned short)r;
}
__device__ __forceinline__ unsigned int pk2bf(float a, float b){
  return (unsigned int)f2bf(a) | ((unsigned int)f2bf(b) << 16);
}
// LDS unit swizzle: r = row (0..127), 2-bit XOR applied to 16B-unit index
__device__ __forceinline__ int swz4(int r){ return (r ^ (r >> 2) ^ (r >> 4)) & 3; }

// unpack 8 bf16 (uint4) -> 8 floats, scaled
__device__ __forceinline__ void unp8s(uint4 w, float* f, float s){
  f[0] = bf2f(w.x & 0xffffu) * s; f[1] = bf2f(w.x >> 16) * s;
  f[2] = bf2f(w.y & 0xffffu) * s; f[3] = bf2f(w.y >> 16) * s;
  f[4] = bf2f(w.z & 0xffffu) * s; f[5] = bf2f(w.z >> 16) * s;
  f[6] = bf2f(w.w & 0xffffu) * s; f[7] = bf2f(w.w >> 16) * s;
}
// unpack 4 fp8 e4m3 (one u32) -> 4 floats (HW cvt)
__device__ __forceinline__ void unpf8(unsigned int w, float* f){
  f32x2_t lo = __builtin_amdgcn_cvt_pk_f32_fp8(w, false);
  f32x2_t hi = __builtin_amdgcn_cvt_pk_f32_fp8(w, true);
  f[0] = lo[0]; f[1] = lo[1]; f[2] = hi[0]; f[3] = hi[1];
}

#define GLOAD16(gsrc, ldst) \
  __builtin_amdgcn_global_load_lds((const __attribute__((address_space(1))) unsigned int*)(gsrc), \
                                   (__attribute__((address_space(3))) unsigned int*)(ldst), 16, 0, 0)

// ---------------- K0: pack weights -> wcatT bf16 [1024][512] PRE-SWIZZLED, biases -> bcat f32[1024]
__global__ void pack_weights(const float* __restrict__ Wq, const float* __restrict__ Wk,
                             const float* __restrict__ Wv, const float* __restrict__ Ws,
                             const float* __restrict__ bq, const float* __restrict__ bk,
                             const float* __restrict__ bv, const float* __restrict__ bs,
                             unsigned short* __restrict__ wcatT, float* __restrict__ bcat){
  int idx = blockIdx.x * 256 + threadIdx.x;
  if (idx < 1024 * 512){
    int c = idx >> 9, k = idx & 511;
    int sel = c >> 8, cc = c & 255;
    const float* W = (sel == 0) ? Wq : (sel == 1) ? Wk : (sel == 2) ? Wv : Ws;
    int p = ((k >> 3) & 3) ^ swz4(c & 127);
    int dst = c * 512 + (k & ~31) + p * 8 + (k & 7);
    wcatT[dst] = f2bf(W[k * 256 + cc]);
  }
  if (idx < 1024){
    int sel = idx >> 8, cc = idx & 255;
    const float* B = (sel == 0) ? bq : (sel == 1) ? bk : (sel == 2) ? bv : bs;
    bcat[idx] = B[cc];
  }
}

// ---------------- K0b: pack Wa1^T -> bf16 [256 cols][256 k]
__global__ void pack_wa1(const float* __restrict__ Wa1, unsigned short* __restrict__ wa1T){
  int idx = blockIdx.x * 256 + threadIdx.x;  // 65536
  int c = idx >> 8, k = idx & 255;
  wa1T[idx] = f2bf(Wa1[k * 256 + c]);
}

// ---------------- K1: x fp32 -> xbf bf16 [n][512] PRE-SWIZZLED (same image layout as wcatT)
__global__ void convert_x(const float* __restrict__ x, unsigned short* __restrict__ xbf, int nunits){
  int idx = blockIdx.x * 256 + threadIdx.x;
  if (idx >= nunits) return;
  int node = idx >> 6, un = idx & 63;
  int k0 = (un >> 2) * 32, u = un & 3;
  const float* src = x + (size_t)node * 512 + k0 + u * 8;
  float4 f0 = *reinterpret_cast<const float4*>(src);
  float4 f1 = *reinterpret_cast<const float4*>(src + 4);
  uint4 o;
  o.x = pk2bf(f0.x, f0.y); o.y = pk2bf(f0.z, f0.w);
  o.z = pk2bf(f1.x, f1.y); o.w = pk2bf(f1.z, f1.w);
  int p = u ^ swz4(node & 127);
  *reinterpret_cast<uint4*>(xbf + (size_t)node * 512 + k0 + p * 8) = o;
}

// ---------------- K3: QKVS GEMM: async gload_lds both operands (pre-swizzled images),
// XCD-swizzled grid, swapped-operand MFMA, bank-uniform LDS-staged epilogue.
// Writes q/s bf16 + k/v fp8.
__global__ __launch_bounds__(256) void gemm_qkvs(const unsigned short* __restrict__ xbf,
                                                 const unsigned short* __restrict__ wcatT,
                                                 const float* __restrict__ bcat,
                                                 unsigned short* __restrict__ qbf,
                                                 unsigned short* __restrict__ sbf,
                                                 unsigned char* __restrict__ kv8,
                                                 int n_nodes, int mblocks){
  __shared__ __align__(16) unsigned char smem[19456];    // K-loop: As 8KB + Bs 8KB; epilogue [64][152] bf16
  unsigned short* As = (unsigned short*)smem;             // [128][32] bf16 (swizzled image)
  unsigned short* Bs = (unsigned short*)(smem + 8192);    // [128][32] bf16 (swizzled image)
  const int tid = threadIdx.x;
  const int lane = tid & 63, wave = tid >> 6;
  const int wm = wave >> 1, wn = wave & 1;
  const int g = (blockIdx.x & 7) * mblocks + (blockIdx.x >> 3);
  const int m_blk = g >> 3, n_blk = g & 7;
  const int m0 = m_blk * 128, n0 = n_blk * 128;
  const int lrow = lane >> 2;
  const int lcol = (lane & 3) * 8;
  const int rA0 = min(m0 + wave * 16 + lrow, n_nodes - 1);
  const int rA1 = min(m0 + (wave + 4) * 16 + lrow, n_nodes - 1);
  const int rB0 = n0 + wave * 16 + lrow;
  const int rB1 = rB0 + 64;
  const int r = lane & 15, q4 = lane >> 4;
  // swizzled fragment read offsets (shorts), hoisted
  int aoff[4], boff[4];
  #pragma unroll
  for (int mi = 0; mi < 4; mi++){ int rr = wm * 64 + mi * 16 + r; aoff[mi] = rr * 32 + ((q4 ^ swz4(rr)) * 8); }
  #pragma unroll
  for (int ni = 0; ni < 4; ni++){ int rb = wn * 64 + ni * 16 + r; boff[ni] = rb * 32 + ((q4 ^ swz4(rb)) * 8); }
  f32x4_t acc[4][4] = {};
  for (int k0 = 0; k0 < 512; k0 += 32){
    GLOAD16(xbf   + (size_t)rA0 * 512 + k0 + lcol, &As[wave * 512]);
    GLOAD16(xbf   + (size_t)rA1 * 512 + k0 + lcol, &As[(wave + 4) * 512]);
    GLOAD16(wcatT + (size_t)rB0 * 512 + k0 + lcol, &Bs[wave * 512]);
    GLOAD16(wcatT + (size_t)rB1 * 512 + k0 + lcol, &Bs[(wave + 4) * 512]);
    __syncthreads();
    bf16x8_t a[4], b[4];
    #pragma unroll
    for (int mi = 0; mi < 4; mi++) a[mi] = *reinterpret_cast<const bf16x8_t*>(&As[aoff[mi]]);
    #pragma unroll
    for (int ni = 0; ni < 4; ni++) b[ni] = *reinterpret_cast<const bf16x8_t*>(&Bs[boff[ni]]);
    // swapped operands: lane holds output row m = r, 4 consecutive n-cols (q4*4+j)
    #pragma unroll
    for (int mi = 0; mi < 4; mi++)
      #pragma unroll
      for (int ni = 0; ni < 4; ni++)
        acc[mi][ni] = __builtin_amdgcn_mfma_f32_16x16x32_bf16(b[ni], a[mi], acc[mi][ni], 0, 0, 0);
    __syncthreads();
  }
  // ---- epilogue: 2 chunks of 64 rows, LDS-staged with bank-uniform strides, coalesced stores ----
  const bool isQ = (n_blk < 2), isS = (n_blk >= 6);
  if (isQ || isS){
    unsigned short* St = (unsigned short*)smem;   // [64][152] bf16 (stride 76 words: uniform banks)
    unsigned short* outp = isQ ? qbf : sbf;
    const int colhalf = isQ ? n_blk : (n_blk - 6);
    #pragma unroll
    for (int ch = 0; ch < 2; ch++){
      if (wm == ch){
        #pragma unroll
        for (int mi = 0; mi < 4; mi++){
          #pragma unroll
          for (int ni = 0; ni < 4; ni++){
            int mloc = mi * 16 + r;
            int nl = wn * 64 + ni * 16 + q4 * 4;
            float4 bb = *reinterpret_cast<const float4*>(&bcat[n0 + nl]);
            uint2 w;
            w.x = pk2bf(acc[mi][ni][0] + bb.x, acc[mi][ni][1] + bb.y);
            w.y = pk2bf(acc[mi][ni][2] + bb.z, acc[mi][ni][3] + bb.w);
            *reinterpret_cast<uint2*>(&St[mloc * 152 + nl]) = w;
          }
        }
      }
      __syncthreads();
      #pragma unroll
      for (int it = 0; it < 4; it++){
        int u = it * 256 + tid;
        int row = u >> 4, seg = (u & 15) * 8;
        int node = m0 + ch * 64 + row;
        if (node < n_nodes){
          uint4 v = *reinterpret_cast<const uint4*>(&St[row * 152 + seg]);
          *reinterpret_cast<uint4*>(outp + (size_t)node * 256 + colhalf * 128 + seg) = v;
        }
      }
      __syncthreads();
    }
  } else {
    unsigned char* St8 = smem;                    // [64][144] fp8 (stride 36 words: uniform banks)
    #pragma unroll
    for (int ch = 0; ch < 2; ch++){
      if (wm == ch){
        #pragma unroll
        for (int mi = 0; mi < 4; mi++){
          #pragma unroll
          for (int ni = 0; ni < 4; ni++){
            int mloc = mi * 16 + r;
            int nl = wn * 64 + ni * 16 + q4 * 4;
            float4 bb = *reinterpret_cast<const float4*>(&bcat[n0 + nl]);
            int u = 0;
            u = __builtin_amdgcn_cvt_pk_fp8_f32(acc[mi][ni][0] + bb.x, acc[mi][ni][1] + bb.y, u, false);
            u = __builtin_amdgcn_cvt_pk_fp8_f32(acc[mi][ni][2] + bb.z, acc[mi][ni][3] + bb.w, u, true);
            *reinterpret_cast<unsigned int*>(&St8[mloc * 144 + nl]) = (unsigned int)u;
          }
        }
      }
      __syncthreads();
      #pragma unroll
      for (int it = 0; it < 2; it++){
        int u = it * 256 + tid;
        int row = u >> 3, seg = (u & 7) * 16;
        int node = m0 + ch * 64 + row;
        if (node < n_nodes){
          uint4 v = *reinterpret_cast<const uint4*>(&St8[row * 144 + seg]);
          *reinterpret_cast<uint4*>(kv8 + (size_t)node * 512 + (n_blk - 2) * 128 + seg) = v;
        }
      }
      __syncthreads();
    }
  }
}

// ---------------- K4: degree histogram
__global__ void degree_hist(const int* __restrict__ ei, int* __restrict__ deg, int ne){
  int i = blockIdx.x * 256 + threadIdx.x;
  if (i < ne) atomicAdd(&deg[ei[ne + i]], 1);
}

// ---------------- K5: exclusive scan, single block, 2-pass blocked
__global__ void scan_deg(const int* __restrict__ deg, int* __restrict__ rowstart, int n, int ne){
  __shared__ int sm[1024];
  int tid = threadIdx.x;
  int per = (n + 1023) / 1024;
  int start = tid * per;
  int sum = 0;
  for (int i = 0; i < per; i++){
    int idx = start + i;
    sum += (idx < n) ? deg[idx] : 0;
  }
  sm[tid] = sum; __syncthreads();
  for (int off = 1; off < 1024; off <<= 1){
    int t = (tid >= off) ? sm[tid - off] : 0;
    __syncthreads();
    sm[tid] += t;
    __syncthreads();
  }
  int run = sm[tid] - sum;
  for (int i = 0; i < per; i++){
    int idx = start + i;
    if (idx < n){
      rowstart[idx] = run;
      run += deg[idx];
    }
  }
  if (tid == 0) rowstart[n] = ne;
}

// ---------------- K6: scatter edges into CSR (stores src*512 byte-offset)
__global__ void scatter_edges(const int* __restrict__ ei, const int* __restrict__ rowstart,
                              int* __restrict__ cursor, int* __restrict__ csrsrc, int ne){
  int i = blockIdx.x * 256 + threadIdx.x;
  if (i < ne){
    int d = ei[ne + i];
    int pos = atomicAdd(&cursor[d], 1);
    csrsrc[rowstart[d] + pos] = ei[i] << 9;
  }
}

// ---------------- K7: per-dst online-softmax aggregation (fp8 K/V, 16 lanes/edge, 4 nodes/wave)
__global__ __launch_bounds__(256) void edge_attn(const unsigned short* __restrict__ qbf,
                                                 const unsigned short* __restrict__ sbf,
                                                 const unsigned char* __restrict__ kv8,
                                                 const int* __restrict__ rowstart,
                                                 const int* __restrict__ csrsrc,
                                                 unsigned short* __restrict__ hbf, int n_nodes){
  const int tid = threadIdx.x;
  const int lane = tid & 63, wave = tid >> 6;
  const int g = lane >> 4, t = lane & 15;
  const int node = blockIdx.x * 16 + wave * 4 + g;
  const bool active = node < n_nodes;
  const int nd = active ? node : 0;
  const float qs = 0.0625f * 1.44269504088896340736f;  // (1/sqrt(256)) * log2(e)
  float q[16];
  {
    const unsigned short* qp = qbf + (size_t)nd * 256 + t * 16;
    uint4 w0 = *reinterpret_cast<const uint4*>(qp);
    uint4 w1 = *reinterpret_cast<const uint4*>(qp + 8);
    unp8s(w0, q, qs); unp8s(w1, q + 8, qs);
  }
  int rs = rowstart[nd];
  int re = active ? rowstart[nd + 1] : rs;
  float m = -1e30f, den = 0.f;
  float acc[16];
  #pragma unroll
  for (int j = 0; j < 16; j++) acc[j] = 0.f;
  for (int i = rs; i < re; i++){
    int soff = csrsrc[i];
    const unsigned char* kb = kv8 + (size_t)soff + t * 16;
    uint4 kw = *reinterpret_cast<const uint4*>(kb);
    float kf[16];
    unpf8(kw.x, kf); unpf8(kw.y, kf + 4); unpf8(kw.z, kf + 8); unpf8(kw.w, kf + 12);
    float s = 0.f;
    #pragma unroll
    for (int j = 0; j < 16; j++) s = fmaf(q[j], kf[j], s);
    s += __shfl_xor(s, 1); s += __shfl_xor(s, 2);
    s += __shfl_xor(s, 4); s += __shfl_xor(s, 8);
    uint4 vw = *reinterpret_cast<const uint4*>(kb + 256);
    float vf[16];
    unpf8(vw.x, vf); unpf8(vw.y, vf + 4); unpf8(vw.z, vf + 8); unpf8(vw.w, vf + 12);
    if (s > m){
      float sc = exp2f(m - s);
      den = den * sc + 1.0f;
      #pragma unroll
      for (int j = 0; j < 16; j++) acc[j] = fmaf(acc[j], sc, vf[j]);
      m = s;
    } else {
      float e = exp2f(s - m);
      den += e;
      #pragma unroll
      for (int j = 0; j < 16; j++) acc[j] = fmaf(e, vf[j], acc[j]);
    }
  }
  float inv = (den > 0.f) ? 1.f / den : 0.f;
  const unsigned short* sp = sbf + (size_t)nd * 256 + t * 16;
  uint4 s0 = *reinterpret_cast<const uint4*>(sp);
  uint4 s1 = *reinterpret_cast<const uint4*>(sp + 8);
  float sf[16]; unp8s(s0, sf, 1.0f); unp8s(s1, sf + 8, 1.0f);
  const float inv_sqrt2 = 0.70710678118654752f;
  unsigned int o[8];
  #pragma unroll
  for (int j = 0; j < 8; j++){
    float h0 = acc[2 * j] * inv + sf[2 * j];
    float h1 = acc[2 * j + 1] * inv + sf[2 * j + 1];
    h0 = 0.5f * h0 * (1.f + erff(h0 * inv_sqrt2));
    h1 = 0.5f * h1 * (1.f + erff(h1 * inv_sqrt2));
    o[j] = (unsigned int)f2bf(h0) | ((unsigned int)f2bf(h1) << 16);
  }
  if (active){
    uint4* dst = reinterpret_cast<uint4*>(hbf + (size_t)node * 256 + t * 16);
    dst[0] = make_uint4(o[0], o[1], o[2], o[3]);
    dst[1] = make_uint4(o[4], o[5], o[6], o[7]);
  }
}

// ---------------- K8: s2[n][2] = tanh(hbf@Wa1 + ba1)@Wa2 + ba2  (bf16 MFMA)
__global__ __launch_bounds__(256) void mlp_mfma(const unsigned short* __restrict__ hbf,
                                                const unsigned short* __restrict__ wa1T,
                                                const float* __restrict__ ba1,
                                                const float* __restrict__ Wa2,
                                                const float* __restrict__ ba2,
                                                float* __restrict__ s2, int n_nodes){
  __shared__ __align__(16) unsigned short As[64 * 72];
  __shared__ float s2s[64][2];
  const int tid = threadIdx.x;
  const int lane = tid & 63, wave = tid >> 6;
  const int m0 = blockIdx.x * 64;
  const int c0 = wave * 64;
  const int r = lane & 15, rg = (lane >> 4) * 4;
  if (tid < 128) s2s[tid >> 1][tid & 1] = 0.f;
  f32x4_t acc[4][4] = {};
  for (int k0 = 0; k0 < 256; k0 += 64){
    int arow = tid >> 2, akc = (tid & 3) * 16;
    uint4 a0v = make_uint4(0,0,0,0), a1v = make_uint4(0,0,0,0);
    if (m0 + arow < n_nodes){
      const unsigned short* src = hbf + (size_t)(m0 + arow) * 256 + k0 + akc;
      a0v = *reinterpret_cast<const uint4*>(src);
      a1v = *reinterpret_cast<const uint4*>(src + 8);
    }
    *reinterpret_cast<uint4*>(&As[arow * 72 + akc]) = a0v;
    *reinterpret_cast<uint4*>(&As[arow * 72 + akc + 8]) = a1v;
    __syncthreads();
    #pragma unroll
    for (int kk = 0; kk < 2; kk++){
      int kg = kk * 32 + (lane >> 4) * 8;
      bf16x8_t a[4], b[4];
      #pragma unroll
      for (int mi = 0; mi < 4; mi++)
        a[mi] = *reinterpret_cast<const bf16x8_t*>(&As[(mi * 16 + r) * 72 + kg]);
      #pragma unroll
      for (int ni = 0; ni < 4; ni++)
        b[ni] = *reinterpret_cast<const bf16x8_t*>(wa1T + (size_t)(c0 + ni * 16 + r) * 256 + k0 + kg);
      #pragma unroll
      for (int mi = 0; mi < 4; mi++)
        #pragma unroll
        for (int ni = 0; ni < 4; ni++)
          acc[mi][ni] = __builtin_amdgcn_mfma_f32_16x16x32_bf16(a[mi], b[ni], acc[mi][ni], 0, 0, 0);
    }
    __syncthreads();
  }
  float w20[4], w21[4], b1c[4];
  #pragma unroll
  for (int ni = 0; ni < 4; ni++){
    int col = c0 + ni * 16 + r;
    w20[ni] = Wa2[col * 2]; w21[ni] = Wa2[col * 2 + 1]; b1c[ni] = ba1[col];
  }
  #pragma unroll
  for (int mi = 0; mi < 4; mi++){
    #pragma unroll
    for (int j = 0; j < 4; j++){
      float t0 = 0.f, t1 = 0.f;
      #pragma unroll
      for (int ni = 0; ni < 4; ni++){
        float t = tanhf(acc[mi][ni][j] + b1c[ni]);
        t0 += t * w20[ni]; t1 += t * w21[ni];
      }
      t0 += __shfl_xor(t0, 1); t0 += __shfl_xor(t0, 2);
      t0 += __shfl_xor(t0, 4); t0 += __shfl_xor(t0, 8);
      t1 += __shfl_xor(t1, 1); t1 += __shfl_xor(t1, 2);
      t1 += __shfl_xor(t1, 4); t1 += __shfl_xor(t1, 8);
      if (r == 0){
        int row = mi * 16 + rg + j;
        atomicAdd(&s2s[row][0], t0);
        atomicAdd(&s2s[row][1], t1);
      }
    }
  }
  __syncthreads();
  if (tid < 128){
    int row = tid >> 1, c = tid & 1;
    int node = m0 + row;
    if (node < n_nodes) s2[node * 2 + c] = s2s[row][c] + ba2[c];
  }
}

// ---------------- K9: column max + exp-sum over n (single block)
__global__ void col_reduce(const float* __restrict__ s2, float* __restrict__ red, int n){
  __shared__ float sm[1024];
  __shared__ float mshare[2];
  int tid = threadIdx.x;
  float mx0 = -INFINITY, mx1 = -INFINITY;
  for (int i = tid; i < n; i += 1024){
    mx0 = fmaxf(mx0, s2[2 * i]);
    mx1 = fmaxf(mx1, s2[2 * i + 1]);
  }
  sm[tid] = mx0; __syncthreads();
  for (int off = 512; off > 0; off >>= 1){
    if (tid < off) sm[tid] = fmaxf(sm[tid], sm[tid + off]);
    __syncthreads();
  }
  if (tid == 0) mshare[0] = sm[0];
  __syncthreads();
  sm[tid] = mx1; __syncthreads();
  for (int off = 512; off > 0; off >>= 1){
    if (tid < off) sm[tid] = fmaxf(sm[tid], sm[tid + off]);
    __syncthreads();
  }
  if (tid == 0) mshare[1] = sm[0];
  __syncthreads();
  float m0 = mshare[0], m1 = mshare[1];
  float s0 = 0.f, s1 = 0.f;
  for (int i = tid; i < n; i += 1024){
    s0 += expf(s2[2 * i] - m0);
    s1 += expf(s2[2 * i + 1] - m1);
  }
  sm[tid] = s0; __syncthreads();
  for (int off = 512; off > 0; off >>= 1){
    if (tid < off) sm[tid] += sm[tid + off];
    __syncthreads();
  }
  float den0 = sm[0];
  __syncthreads();
  sm[tid] = s1; __syncthreads();
  for (int off = 512; off > 0; off >>= 1){
    if (tid < off) sm[tid] += sm[tid + off];
    __syncthreads();
  }
  if (tid == 0){
    red[0] = m0; red[1] = m1; red[2] = den0; red[3] = sm[0];
  }
}

// ---------------- K10: attn, A output, M partial accumulation (reads bf16 h)
__global__ __launch_bounds__(256) void attn_M(const float* __restrict__ s2, const float* __restrict__ red,
                                              const unsigned short* __restrict__ hbf, const int* __restrict__ label,
                                              float* __restrict__ Mbuf, float* __restrict__ outA, int n){
  __shared__ float a0s[256], a1s[256];
  int tid = threadIdx.x;
  int n0 = blockIdx.x * 256;
  int node = n0 + tid;
  float m0 = red[0], m1 = red[1];
  float i0 = 1.f / red[2], i1 = 1.f / red[3];
  float a0 = 0.f, a1 = 0.f;
  if (node < n){
    a0 = expf(s2[2 * node] - m0) * i0;
    a1 = expf(s2[2 * node + 1] - m1) * i1;
    outA[node] = (label[0] == 0) ? a0 : a1;
  }
  a0s[tid] = a0; a1s[tid] = a1;
  __syncthreads();
  int d = tid;
  float M0 = 0.f, M1 = 0.f;
  int cnt = min(256, n - n0);
  for (int i = 0; i < cnt; i++){
    float hv = bf2f((unsigned int)hbf[(size_t)(n0 + i) * 256 + d]);
    M0 += a0s[i] * hv;
    M1 += a1s[i] * hv;
  }
  atomicAdd(&Mbuf[d], M0);
  atomicAdd(&Mbuf[256 + d], M1);
}

// ---------------- K11: logits + Y_prob
__global__ void final_k(const float* __restrict__ Mbuf, const float* __restrict__ Wc,
                        const float* __restrict__ bc, float* __restrict__ out){
  __shared__ float sm[256];
  __shared__ float l0s;
  int tid = threadIdx.x;
  float p0 = Mbuf[tid] * Wc[tid];
  float p1 = Mbuf[256 + tid] * Wc[256 + tid];
  sm[tid] = p0; __syncthreads();
  for (int off = 128; off > 0; off >>= 1){
    if (tid < off) sm[tid] += sm[tid + off];
    __syncthreads();
  }
  if (tid == 0) l0s = sm[0];
  __syncthreads();
  sm[tid] = p1; __syncthreads();
  for (int off = 128; off > 0; off >>= 1){
    if (tid < off) sm[tid] += sm[tid + off];
    __syncthreads();
  }
  if (tid == 0){
    float l0 = l0s + bc[0];
    float l1 = sm[0] + bc[1];
    out[0] = l0; out[1] = l1;
    float mx = fmaxf(l0, l1);
    float e0 = expf(l0 - mx), e1 = expf(l1 - mx);
    float inv = 1.f / (e0 + e1);
    out[2] = e0 * inv; out[3] = e1 * inv;
  }
}

extern "C" void kernel_launch(void* const* d_in, const int* in_sizes, int n_in,
                              void* d_out, int out_size, void* d_ws, size_t ws_size,
                              hipStream_t stream) {
  const float* x   = (const float*)d_in[0];
  const int*   ei  = (const int*)d_in[1];
  const int*   lab = (const int*)d_in[2];
  const float* Wq  = (const float*)d_in[3];
  const float* bq  = (const float*)d_in[4];
  const float* Wk  = (const float*)d_in[5];
  const float* bk  = (const float*)d_in[6];
  const float* Wv  = (const float*)d_in[7];
  const float* bv  = (const float*)d_in[8];
  const float* Ws  = (const float*)d_in[9];
  const float* bs  = (const float*)d_in[10];
  const float* Wa1 = (const float*)d_in[11];
  const float* ba1 = (const float*)d_in[12];
  const float* Wa2 = (const float*)d_in[13];
  const float* ba2 = (const float*)d_in[14];
  const float* Wc  = (const float*)d_in[15];
  const float* bc  = (const float*)d_in[16];
  float* out = (float*)d_out;

  const int n  = in_sizes[0] / 512;   // 20000
  const int ne = in_sizes[1] / 2;     // 320000

  char* ws = (char*)d_ws;
  size_t off = 0;
  auto take = [&](size_t bytes){ size_t r = off; off += (bytes + 255) & ~(size_t)255; return r; };
  unsigned short* wcatT  = (unsigned short*)(ws + take((size_t)1024 * 512 * 2));
  float*          bcat   = (float*)(ws + take(1024 * 4));
  unsigned short* xbf    = (unsigned short*)(ws + take((size_t)n * 512 * 2));
  unsigned short* qbf    = (unsigned short*)(ws + take((size_t)n * 256 * 2));
  unsigned short* sbf    = (unsigned short*)(ws + take((size_t)n * 256 * 2));
  unsigned char*  kv8    = (unsigned char*)(ws + take((size_t)n * 512));
  unsigned short* hbf    = (unsigned short*)(ws + take((size_t)n * 256 * 2));
  unsigned short* wa1T   = (unsigned short*)(ws + take((size_t)256 * 256 * 2));
  float*          s2     = (float*)(ws + take((size_t)n * 2 * 4));
  size_t zoff = off;
  int*            deg    = (int*)(ws + take((size_t)n * 4));
  int*            cursor = (int*)(ws + take((size_t)n * 4));
  float*          Mbuf   = (float*)(ws + take(512 * 4));
  size_t zlen = off - zoff;
  int*            rowst  = (int*)(ws + take((size_t)(n + 1) * 4));
  int*            csrsrc = (int*)(ws + take((size_t)ne * 4));
  float*          red    = (float*)(ws + take(4 * 4));

  hipMemsetAsync(ws + zoff, 0, zlen, stream);

  pack_weights<<<(1024 * 512 + 255) / 256, 256, 0, stream>>>(Wq, Wk, Wv, Ws, bq, bk, bv, bs, wcatT, bcat);
  pack_wa1<<<256, 256, 0, stream>>>(Wa1, wa1T);
  convert_x<<<(n * 64 + 255) / 256, 256, 0, stream>>>(x, xbf, n * 64);
  const int mblocks = (n + 127) / 128;
  gemm_qkvs<<<8 * mblocks, 256, 0, stream>>>(xbf, wcatT, bcat, qbf, sbf, kv8, n, mblocks);
  degree_hist<<<(ne + 255) / 256, 256, 0, stream>>>(ei, deg, ne);
  scan_deg<<<1, 1024, 0, stream>>>(deg, rowst, n, ne);
  scatter_edges<<<(ne + 255) / 256, 256, 0, stream>>>(ei, rowst, cursor, csrsrc, ne);
  edge_attn<<<(n + 15) / 16, 256, 0, stream>>>(qbf, sbf, kv8, rowst, csrsrc, hbf, n);
  mlp_mfma<<<(n + 63) / 64, 256, 0, stream>>>(hbf, wa1T, ba1, Wa2, ba2, s2, n);
  col_reduce<<<1, 1024, 0, stream>>>(s2, red, n);
  attn_M<<<(n + 255) / 256, 256, 0, stream>>>(s2, red, hbf, lab, Mbuf, out + 4, n);
  final_k<<<1, 256, 0, stream>>>(Mbuf, Wc, bc, out);
  (void)ws_size; (void)out_size; (void)n_in;
}

// Round 7
// 211.528 us; speedup vs baseline: 1.1059x; 1.0735x over previous
//
#include <hip/hip_runtime.h>
#include <hip/hip_bf16.h>
#include <math.h>

typedef float f32x4_t __attribute__((ext_vector_type(4)));
typedef float f32x2_t __attribute__((ext_vector_type(2)));
typedef __bf16 bf16x8_t __attribute__((ext_vector_type(8)));

__device__ __forceinline__ float bf2f(unsigned int u){
  union { float f; unsigned int i; } x; x.i = u << 16; return x.f;
}
__device__ __forceinline__ unsigned short f2bf(float f){
  unsigned int x = __float_as_uint(f);
  unsigned int r = (x + 0x7fffu + ((x >> 16) & 1u)) >> 16;
  return (unsigned short)r;
}
__device__ __forceinline__ unsigned int pk2bf(float a, float b){
  return (unsigned int)f2bf(a) | ((unsigned int)f2bf(b) << 16);
}
// LDS unit swizzle: r = row (0..127), 2-bit XOR applied to 16B-unit index
__device__ __forceinline__ int swz4(int r){ return (r ^ (r >> 2) ^ (r >> 4)) & 3; }

// unpack 8 bf16 (uint4) -> 8 floats, scaled
__device__ __forceinline__ void unp8s(uint4 w, float* f, float s){
  f[0] = bf2f(w.x & 0xffffu) * s; f[1] = bf2f(w.x >> 16) * s;
  f[2] = bf2f(w.y & 0xffffu) * s; f[3] = bf2f(w.y >> 16) * s;
  f[4] = bf2f(w.z & 0xffffu) * s; f[5] = bf2f(w.z >> 16) * s;
  f[6] = bf2f(w.w & 0xffffu) * s; f[7] = bf2f(w.w >> 16) * s;
}
// unpack 4 fp8 e4m3 (one u32) -> 4 floats (HW cvt)
__device__ __forceinline__ void unpf8(unsigned int w, float* f){
  f32x2_t lo = __builtin_amdgcn_cvt_pk_f32_fp8(w, false);
  f32x2_t hi = __builtin_amdgcn_cvt_pk_f32_fp8(w, true);
  f[0] = lo[0]; f[1] = lo[1]; f[2] = hi[0]; f[3] = hi[1];
}

#define GLOAD16(gsrc, ldst) \
  __builtin_amdgcn_global_load_lds((const __attribute__((address_space(1))) unsigned int*)(gsrc), \
                                   (__attribute__((address_space(3))) unsigned int*)(ldst), 16, 0, 0)

// ---------------- K0: pack weights -> wcatT bf16 [1024][512] PRE-SWIZZLED, biases -> bcat f32[1024]
__global__ void pack_weights(const float* __restrict__ Wq, const float* __restrict__ Wk,
                             const float* __restrict__ Wv, const float* __restrict__ Ws,
                             const float* __restrict__ bq, const float* __restrict__ bk,
                             const float* __restrict__ bv, const float* __restrict__ bs,
                             unsigned short* __restrict__ wcatT, float* __restrict__ bcat){
  int idx = blockIdx.x * 256 + threadIdx.x;
  if (idx < 1024 * 512){
    int c = idx >> 9, k = idx & 511;
    int sel = c >> 8, cc = c & 255;
    const float* W = (sel == 0) ? Wq : (sel == 1) ? Wk : (sel == 2) ? Wv : Ws;
    int p = ((k >> 3) & 3) ^ swz4(c & 127);
    int dst = c * 512 + (k & ~31) + p * 8 + (k & 7);
    wcatT[dst] = f2bf(W[k * 256 + cc]);
  }
  if (idx < 1024){
    int sel = idx >> 8, cc = idx & 255;
    const float* B = (sel == 0) ? bq : (sel == 1) ? bk : (sel == 2) ? bv : bs;
    bcat[idx] = B[cc];
  }
}

// ---------------- K0b: pack Wa1^T -> bf16 [256 cols][256 k]
__global__ void pack_wa1(const float* __restrict__ Wa1, unsigned short* __restrict__ wa1T){
  int idx = blockIdx.x * 256 + threadIdx.x;  // 65536
  int c = idx >> 8, k = idx & 255;
  wa1T[idx] = f2bf(Wa1[k * 256 + c]);
}

// ---------------- K1: x fp32 -> xbf bf16 [n][512] PRE-SWIZZLED (same image layout as wcatT)
__global__ void convert_x(const float* __restrict__ x, unsigned short* __restrict__ xbf, int nunits){
  int idx = blockIdx.x * 256 + threadIdx.x;
  if (idx >= nunits) return;
  int node = idx >> 6, un = idx & 63;
  int k0 = (un >> 2) * 32, u = un & 3;
  const float* src = x + (size_t)node * 512 + k0 + u * 8;
  float4 f0 = *reinterpret_cast<const float4*>(src);
  float4 f1 = *reinterpret_cast<const float4*>(src + 4);
  uint4 o;
  o.x = pk2bf(f0.x, f0.y); o.y = pk2bf(f0.z, f0.w);
  o.z = pk2bf(f1.x, f1.y); o.w = pk2bf(f1.z, f1.w);
  int p = u ^ swz4(node & 127);
  *reinterpret_cast<uint4*>(xbf + (size_t)node * 512 + k0 + p * 8) = o;
}

// ---------------- K3: QKVS GEMM: double-buffered async gload_lds (pre-swizzled images),
// counted vmcnt + raw barriers (2-phase pipeline), XCD-swizzled grid, swapped-operand MFMA,
// bank-uniform LDS-staged epilogue. Writes q/s bf16 + k/v fp8.
__global__ __launch_bounds__(256) void gemm_qkvs(const unsigned short* __restrict__ xbf,
                                                 const unsigned short* __restrict__ wcatT,
                                                 const float* __restrict__ bcat,
                                                 unsigned short* __restrict__ qbf,
                                                 unsigned short* __restrict__ sbf,
                                                 unsigned char* __restrict__ kv8,
                                                 int n_nodes, int mblocks){
  __shared__ __align__(16) unsigned char smem[32768];    // 2 x (As 8KB + Bs 8KB); epilogue reuses
  const int tid = threadIdx.x;
  const int lane = tid & 63, wave = tid >> 6;
  const int wm = wave >> 1, wn = wave & 1;
  const int g = (blockIdx.x & 7) * mblocks + (blockIdx.x >> 3);
  const int m_blk = g >> 3, n_blk = g & 7;
  const int m0 = m_blk * 128, n0 = n_blk * 128;
  const int lrow = lane >> 2;
  const int lcol = (lane & 3) * 8;
  const int rA0 = min(m0 + wave * 16 + lrow, n_nodes - 1);
  const int rA1 = min(m0 + (wave + 4) * 16 + lrow, n_nodes - 1);
  const int rB0 = n0 + wave * 16 + lrow;
  const int rB1 = rB0 + 64;
  const int r = lane & 15, q4 = lane >> 4;
  const unsigned short* aG0 = xbf   + (size_t)rA0 * 512 + lcol;
  const unsigned short* aG1 = xbf   + (size_t)rA1 * 512 + lcol;
  const unsigned short* bG0 = wcatT + (size_t)rB0 * 512 + lcol;
  const unsigned short* bG1 = wcatT + (size_t)rB1 * 512 + lcol;
  // buffers: buf b -> As at smem + b*16384, Bs at smem + b*16384 + 8192
  // swizzled fragment read offsets (shorts within a tile)
  int aoff[4], boff[4];
  #pragma unroll
  for (int mi = 0; mi < 4; mi++){ int rr = wm * 64 + mi * 16 + r; aoff[mi] = rr * 32 + ((q4 ^ swz4(rr)) * 8); }
  #pragma unroll
  for (int ni = 0; ni < 4; ni++){ int rb = wn * 64 + ni * 16 + r; boff[ni] = rb * 32 + ((q4 ^ swz4(rb)) * 8); }
  f32x4_t acc[4][4] = {};
#define STAGE(buf, k0) { \
    unsigned short* As_ = (unsigned short*)(smem + (buf) * 16384); \
    unsigned short* Bs_ = (unsigned short*)(smem + (buf) * 16384 + 8192); \
    GLOAD16(aG0 + (k0), &As_[wave * 512]); \
    GLOAD16(aG1 + (k0), &As_[(wave + 4) * 512]); \
    GLOAD16(bG0 + (k0), &Bs_[wave * 512]); \
    GLOAD16(bG1 + (k0), &Bs_[(wave + 4) * 512]); \
  }
  STAGE(0, 0);
  int cur = 0;
  #pragma unroll 4
  for (int t = 0; t < 16; t++){
    if (t < 15){
      STAGE(cur ^ 1, (t + 1) * 32);
      asm volatile("s_waitcnt vmcnt(4)" ::: "memory");   // wait only for buf[cur]'s 4 loads
    } else {
      asm volatile("s_waitcnt vmcnt(0)" ::: "memory");
    }
    __builtin_amdgcn_s_barrier();
    asm volatile("" ::: "memory");                        // keep ds_reads below the barrier
    const unsigned short* As = (const unsigned short*)(smem + cur * 16384);
    const unsigned short* Bs = (const unsigned short*)(smem + cur * 16384 + 8192);
    bf16x8_t a[4], b[4];
    #pragma unroll
    for (int mi = 0; mi < 4; mi++) a[mi] = *reinterpret_cast<const bf16x8_t*>(&As[aoff[mi]]);
    #pragma unroll
    for (int ni = 0; ni < 4; ni++) b[ni] = *reinterpret_cast<const bf16x8_t*>(&Bs[boff[ni]]);
    // swapped operands: lane holds output row m = r, 4 consecutive n-cols (q4*4+j)
    #pragma unroll
    for (int mi = 0; mi < 4; mi++)
      #pragma unroll
      for (int ni = 0; ni < 4; ni++)
        acc[mi][ni] = __builtin_amdgcn_mfma_f32_16x16x32_bf16(b[ni], a[mi], acc[mi][ni], 0, 0, 0);
    __builtin_amdgcn_s_barrier();                         // all waves done reading buf[cur]
    asm volatile("" ::: "memory");
    cur ^= 1;
  }
#undef STAGE
  // ---- epilogue: 2 chunks of 64 rows, LDS-staged with bank-uniform strides, coalesced stores ----
  const bool isQ = (n_blk < 2), isS = (n_blk >= 6);
  if (isQ || isS){
    unsigned short* St = (unsigned short*)smem;   // [64][152] bf16
    unsigned short* outp = isQ ? qbf : sbf;
    const int colhalf = isQ ? n_blk : (n_blk - 6);
    #pragma unroll
    for (int ch = 0; ch < 2; ch++){
      if (wm == ch){
        #pragma unroll
        for (int mi = 0; mi < 4; mi++){
          #pragma unroll
          for (int ni = 0; ni < 4; ni++){
            int mloc = mi * 16 + r;
            int nl = wn * 64 + ni * 16 + q4 * 4;
            float4 bb = *reinterpret_cast<const float4*>(&bcat[n0 + nl]);
            uint2 w;
            w.x = pk2bf(acc[mi][ni][0] + bb.x, acc[mi][ni][1] + bb.y);
            w.y = pk2bf(acc[mi][ni][2] + bb.z, acc[mi][ni][3] + bb.w);
            *reinterpret_cast<uint2*>(&St[mloc * 152 + nl]) = w;
          }
        }
      }
      __syncthreads();
      #pragma unroll
      for (int it = 0; it < 4; it++){
        int u = it * 256 + tid;
        int row = u >> 4, seg = (u & 15) * 8;
        int node = m0 + ch * 64 + row;
        if (node < n_nodes){
          uint4 v = *reinterpret_cast<const uint4*>(&St[row * 152 + seg]);
          *reinterpret_cast<uint4*>(outp + (size_t)node * 256 + colhalf * 128 + seg) = v;
        }
      }
      __syncthreads();
    }
  } else {
    unsigned char* St8 = smem;                    // [64][144] fp8
    #pragma unroll
    for (int ch = 0; ch < 2; ch++){
      if (wm == ch){
        #pragma unroll
        for (int mi = 0; mi < 4; mi++){
          #pragma unroll
          for (int ni = 0; ni < 4; ni++){
            int mloc = mi * 16 + r;
            int nl = wn * 64 + ni * 16 + q4 * 4;
            float4 bb = *reinterpret_cast<const float4*>(&bcat[n0 + nl]);
            int u = 0;
            u = __builtin_amdgcn_cvt_pk_fp8_f32(acc[mi][ni][0] + bb.x, acc[mi][ni][1] + bb.y, u, false);
            u = __builtin_amdgcn_cvt_pk_fp8_f32(acc[mi][ni][2] + bb.z, acc[mi][ni][3] + bb.w, u, true);
            *reinterpret_cast<unsigned int*>(&St8[mloc * 144 + nl]) = (unsigned int)u;
          }
        }
      }
      __syncthreads();
      #pragma unroll
      for (int it = 0; it < 2; it++){
        int u = it * 256 + tid;
        int row = u >> 3, seg = (u & 7) * 16;
        int node = m0 + ch * 64 + row;
        if (node < n_nodes){
          uint4 v = *reinterpret_cast<const uint4*>(&St8[row * 144 + seg]);
          *reinterpret_cast<uint4*>(kv8 + (size_t)node * 512 + (n_blk - 2) * 128 + seg) = v;
        }
      }
      __syncthreads();
    }
  }
}

// ---------------- K4: degree histogram
__global__ void degree_hist(const int* __restrict__ ei, int* __restrict__ deg, int ne){
  int i = blockIdx.x * 256 + threadIdx.x;
  if (i < ne) atomicAdd(&deg[ei[ne + i]], 1);
}

// ---------------- K5: exclusive scan, single block, 2-pass blocked
__global__ void scan_deg(const int* __restrict__ deg, int* __restrict__ rowstart, int n, int ne){
  __shared__ int sm[1024];
  int tid = threadIdx.x;
  int per = (n + 1023) / 1024;
  int start = tid * per;
  int sum = 0;
  for (int i = 0; i < per; i++){
    int idx = start + i;
    sum += (idx < n) ? deg[idx] : 0;
  }
  sm[tid] = sum; __syncthreads();
  for (int off = 1; off < 1024; off <<= 1){
    int t = (tid >= off) ? sm[tid - off] : 0;
    __syncthreads();
    sm[tid] += t;
    __syncthreads();
  }
  int run = sm[tid] - sum;
  for (int i = 0; i < per; i++){
    int idx = start + i;
    if (idx < n){
      rowstart[idx] = run;
      run += deg[idx];
    }
  }
  if (tid == 0) rowstart[n] = ne;
}

// ---------------- K6: scatter edges into CSR (stores src*512 byte-offset)
__global__ void scatter_edges(const int* __restrict__ ei, const int* __restrict__ rowstart,
                              int* __restrict__ cursor, int* __restrict__ csrsrc, int ne){
  int i = blockIdx.x * 256 + threadIdx.x;
  if (i < ne){
    int d = ei[ne + i];
    int pos = atomicAdd(&cursor[d], 1);
    csrsrc[rowstart[d] + pos] = ei[i] << 9;
  }
}

// ---------------- K7: per-dst online-softmax aggregation (fp8 K/V, 16 lanes/edge, 4 nodes/wave,
// next-edge prefetch, branchless online-softmax update)
__global__ __launch_bounds__(256) void edge_attn(const unsigned short* __restrict__ qbf,
                                                 const unsigned short* __restrict__ sbf,
                                                 const unsigned char* __restrict__ kv8,
                                                 const int* __restrict__ rowstart,
                                                 const int* __restrict__ csrsrc,
                                                 unsigned short* __restrict__ hbf, int n_nodes){
  const int tid = threadIdx.x;
  const int lane = tid & 63, wave = tid >> 6;
  const int g = lane >> 4, t = lane & 15;
  const int node = blockIdx.x * 16 + wave * 4 + g;
  const bool active = node < n_nodes;
  const int nd = active ? node : 0;
  const float qs = 0.0625f * 1.44269504088896340736f;  // (1/sqrt(256)) * log2(e)
  float q[16];
  {
    const unsigned short* qp = qbf + (size_t)nd * 256 + t * 16;
    uint4 w0 = *reinterpret_cast<const uint4*>(qp);
    uint4 w1 = *reinterpret_cast<const uint4*>(qp + 8);
    unp8s(w0, q, qs); unp8s(w1, q + 8, qs);
  }
  int rs = rowstart[nd];
  int re = active ? rowstart[nd + 1] : rs;
  float m = -1e30f, den = 0.f;
  float acc[16];
  #pragma unroll
  for (int j = 0; j < 16; j++) acc[j] = 0.f;
  uint4 kw, vw;
  if (rs < re){
    const unsigned char* kb = kv8 + (size_t)csrsrc[rs] + t * 16;
    kw = *reinterpret_cast<const uint4*>(kb);
    vw = *reinterpret_cast<const uint4*>(kb + 256);
  }
  for (int i = rs; i < re; i++){
    uint4 kwc = kw, vwc = vw;
    if (i + 1 < re){            // prefetch next edge's K/V (hides gather latency)
      const unsigned char* kb = kv8 + (size_t)csrsrc[i + 1] + t * 16;
      kw = *reinterpret_cast<const uint4*>(kb);
      vw = *reinterpret_cast<const uint4*>(kb + 256);
    }
    float kf[16];
    unpf8(kwc.x, kf); unpf8(kwc.y, kf + 4); unpf8(kwc.z, kf + 8); unpf8(kwc.w, kf + 12);
    float s = 0.f;
    #pragma unroll
    for (int j = 0; j < 16; j++) s = fmaf(q[j], kf[j], s);
    s += __shfl_xor(s, 1); s += __shfl_xor(s, 2);
    s += __shfl_xor(s, 4); s += __shfl_xor(s, 8);
    float vf[16];
    unpf8(vwc.x, vf); unpf8(vwc.y, vf + 4); unpf8(vwc.z, vf + 8); unpf8(vwc.w, vf + 12);
    float mn = fmaxf(m, s);
    float sc = exp2f(m - mn);   // branchless: no 16-lane-group divergence
    float e  = exp2f(s - mn);
    den = den * sc + e;
    #pragma unroll
    for (int j = 0; j < 16; j++) acc[j] = fmaf(acc[j], sc, e * vf[j]);
    m = mn;
  }
  float inv = (den > 0.f) ? 1.f / den : 0.f;
  const unsigned short* sp = sbf + (size_t)nd * 256 + t * 16;
  uint4 s0 = *reinterpret_cast<const uint4*>(sp);
  uint4 s1 = *reinterpret_cast<const uint4*>(sp + 8);
  float sf[16]; unp8s(s0, sf, 1.0f); unp8s(s1, sf + 8, 1.0f);
  const float inv_sqrt2 = 0.70710678118654752f;
  unsigned int o[8];
  #pragma unroll
  for (int j = 0; j < 8; j++){
    float h0 = acc[2 * j] * inv + sf[2 * j];
    float h1 = acc[2 * j + 1] * inv + sf[2 * j + 1];
    h0 = 0.5f * h0 * (1.f + erff(h0 * inv_sqrt2));
    h1 = 0.5f * h1 * (1.f + erff(h1 * inv_sqrt2));
    o[j] = (unsigned int)f2bf(h0) | ((unsigned int)f2bf(h1) << 16);
  }
  if (active){
    uint4* dst = reinterpret_cast<uint4*>(hbf + (size_t)node * 256 + t * 16);
    dst[0] = make_uint4(o[0], o[1], o[2], o[3]);
    dst[1] = make_uint4(o[4], o[5], o[6], o[7]);
  }
}

// ---------------- K8: s2[n][2] = tanh(hbf@Wa1 + ba1)@Wa2 + ba2  (bf16 MFMA)
__global__ __launch_bounds__(256) void mlp_mfma(const unsigned short* __restrict__ hbf,
                                                const unsigned short* __restrict__ wa1T,
                                                const float* __restrict__ ba1,
                                                const float* __restrict__ Wa2,
                                                const float* __restrict__ ba2,
                                                float* __restrict__ s2, int n_nodes){
  __shared__ __align__(16) unsigned short As[64 * 72];
  __shared__ float s2s[64][2];
  const int tid = threadIdx.x;
  const int lane = tid & 63, wave = tid >> 6;
  const int m0 = blockIdx.x * 64;
  const int c0 = wave * 64;
  const int r = lane & 15, rg = (lane >> 4) * 4;
  if (tid < 128) s2s[tid >> 1][tid & 1] = 0.f;
  f32x4_t acc[4][4] = {};
  for (int k0 = 0; k0 < 256; k0 += 64){
    int arow = tid >> 2, akc = (tid & 3) * 16;
    uint4 a0v = make_uint4(0,0,0,0), a1v = make_uint4(0,0,0,0);
    if (m0 + arow < n_nodes){
      const unsigned short* src = hbf + (size_t)(m0 + arow) * 256 + k0 + akc;
      a0v = *reinterpret_cast<const uint4*>(src);
      a1v = *reinterpret_cast<const uint4*>(src + 8);
    }
    *reinterpret_cast<uint4*>(&As[arow * 72 + akc]) = a0v;
    *reinterpret_cast<uint4*>(&As[arow * 72 + akc + 8]) = a1v;
    __syncthreads();
    #pragma unroll
    for (int kk = 0; kk < 2; kk++){
      int kg = kk * 32 + (lane >> 4) * 8;
      bf16x8_t a[4], b[4];
      #pragma unroll
      for (int mi = 0; mi < 4; mi++)
        a[mi] = *reinterpret_cast<const bf16x8_t*>(&As[(mi * 16 + r) * 72 + kg]);
      #pragma unroll
      for (int ni = 0; ni < 4; ni++)
        b[ni] = *reinterpret_cast<const bf16x8_t*>(wa1T + (size_t)(c0 + ni * 16 + r) * 256 + k0 + kg);
      #pragma unroll
      for (int mi = 0; mi < 4; mi++)
        #pragma unroll
        for (int ni = 0; ni < 4; ni++)
          acc[mi][ni] = __builtin_amdgcn_mfma_f32_16x16x32_bf16(a[mi], b[ni], acc[mi][ni], 0, 0, 0);
    }
    __syncthreads();
  }
  float w20[4], w21[4], b1c[4];
  #pragma unroll
  for (int ni = 0; ni < 4; ni++){
    int col = c0 + ni * 16 + r;
    w20[ni] = Wa2[col * 2]; w21[ni] = Wa2[col * 2 + 1]; b1c[ni] = ba1[col];
  }
  #pragma unroll
  for (int mi = 0; mi < 4; mi++){
    #pragma unroll
    for (int j = 0; j < 4; j++){
      float t0 = 0.f, t1 = 0.f;
      #pragma unroll
      for (int ni = 0; ni < 4; ni++){
        float t = tanhf(acc[mi][ni][j] + b1c[ni]);
        t0 += t * w20[ni]; t1 += t * w21[ni];
      }
      t0 += __shfl_xor(t0, 1); t0 += __shfl_xor(t0, 2);
      t0 += __shfl_xor(t0, 4); t0 += __shfl_xor(t0, 8);
      t1 += __shfl_xor(t1, 1); t1 += __shfl_xor(t1, 2);
      t1 += __shfl_xor(t1, 4); t1 += __shfl_xor(t1, 8);
      if (r == 0){
        int row = mi * 16 + rg + j;
        atomicAdd(&s2s[row][0], t0);
        atomicAdd(&s2s[row][1], t1);
      }
    }
  }
  __syncthreads();
  if (tid < 128){
    int row = tid >> 1, c = tid & 1;
    int node = m0 + row;
    if (node < n_nodes) s2[node * 2 + c] = s2s[row][c] + ba2[c];
  }
}

// ---------------- K9: column max + exp-sum over n (single block)
__global__ void col_reduce(const float* __restrict__ s2, float* __restrict__ red, int n){
  __shared__ float sm[1024];
  __shared__ float mshare[2];
  int tid = threadIdx.x;
  float mx0 = -INFINITY, mx1 = -INFINITY;
  for (int i = tid; i < n; i += 1024){
    mx0 = fmaxf(mx0, s2[2 * i]);
    mx1 = fmaxf(mx1, s2[2 * i + 1]);
  }
  sm[tid] = mx0; __syncthreads();
  for (int off = 512; off > 0; off >>= 1){
    if (tid < off) sm[tid] = fmaxf(sm[tid], sm[tid + off]);
    __syncthreads();
  }
  if (tid == 0) mshare[0] = sm[0];
  __syncthreads();
  sm[tid] = mx1; __syncthreads();
  for (int off = 512; off > 0; off >>= 1){
    if (tid < off) sm[tid] = fmaxf(sm[tid], sm[tid + off]);
    __syncthreads();
  }
  if (tid == 0) mshare[1] = sm[0];
  __syncthreads();
  float m0 = mshare[0], m1 = mshare[1];
  float s0 = 0.f, s1 = 0.f;
  for (int i = tid; i < n; i += 1024){
    s0 += expf(s2[2 * i] - m0);
    s1 += expf(s2[2 * i + 1] - m1);
  }
  sm[tid] = s0; __syncthreads();
  for (int off = 512; off > 0; off >>= 1){
    if (tid < off) sm[tid] += sm[tid + off];
    __syncthreads();
  }
  float den0 = sm[0];
  __syncthreads();
  sm[tid] = s1; __syncthreads();
  for (int off = 512; off > 0; off >>= 1){
    if (tid < off) sm[tid] += sm[tid + off];
    __syncthreads();
  }
  if (tid == 0){
    red[0] = m0; red[1] = m1; red[2] = den0; red[3] = sm[0];
  }
}

// ---------------- K10: attn, A output, M partial accumulation (reads bf16 h)
__global__ __launch_bounds__(256) void attn_M(const float* __restrict__ s2, const float* __restrict__ red,
                                              const unsigned short* __restrict__ hbf, const int* __restrict__ label,
                                              float* __restrict__ Mbuf, float* __restrict__ outA, int n){
  __shared__ float a0s[256], a1s[256];
  int tid = threadIdx.x;
  int n0 = blockIdx.x * 256;
  int node = n0 + tid;
  float m0 = red[0], m1 = red[1];
  float i0 = 1.f / red[2], i1 = 1.f / red[3];
  float a0 = 0.f, a1 = 0.f;
  if (node < n){
    a0 = expf(s2[2 * node] - m0) * i0;
    a1 = expf(s2[2 * node + 1] - m1) * i1;
    outA[node] = (label[0] == 0) ? a0 : a1;
  }
  a0s[tid] = a0; a1s[tid] = a1;
  __syncthreads();
  int d = tid;
  float M0 = 0.f, M1 = 0.f;
  int cnt = min(256, n - n0);
  for (int i = 0; i < cnt; i++){
    float hv = bf2f((unsigned int)hbf[(size_t)(n0 + i) * 256 + d]);
    M0 += a0s[i] * hv;
    M1 += a1s[i] * hv;
  }
  atomicAdd(&Mbuf[d], M0);
  atomicAdd(&Mbuf[256 + d], M1);
}

// ---------------- K11: logits + Y_prob
__global__ void final_k(const float* __restrict__ Mbuf, const float* __restrict__ Wc,
                        const float* __restrict__ bc, float* __restrict__ out){
  __shared__ float sm[256];
  __shared__ float l0s;
  int tid = threadIdx.x;
  float p0 = Mbuf[tid] * Wc[tid];
  float p1 = Mbuf[256 + tid] * Wc[256 + tid];
  sm[tid] = p0; __syncthreads();
  for (int off = 128; off > 0; off >>= 1){
    if (tid < off) sm[tid] += sm[tid + off];
    __syncthreads();
  }
  if (tid == 0) l0s = sm[0];
  __syncthreads();
  sm[tid] = p1; __syncthreads();
  for (int off = 128; off > 0; off >>= 1){
    if (tid < off) sm[tid] += sm[tid + off];
    __syncthreads();
  }
  if (tid == 0){
    float l0 = l0s + bc[0];
    float l1 = sm[0] + bc[1];
    out[0] = l0; out[1] = l1;
    float mx = fmaxf(l0, l1);
    float e0 = expf(l0 - mx), e1 = expf(l1 - mx);
    float inv = 1.f / (e0 + e1);
    out[2] = e0 * inv; out[3] = e1 * inv;
  }
}

extern "C" void kernel_launch(void* const* d_in, const int* in_sizes, int n_in,
                              void* d_out, int out_size, void* d_ws, size_t ws_size,
                              hipStream_t stream) {
  const float* x   = (const float*)d_in[0];
  const int*   ei  = (const int*)d_in[1];
  const int*   lab = (const int*)d_in[2];
  const float* Wq  = (const float*)d_in[3];
  const float* bq  = (const float*)d_in[4];
  const float* Wk  = (const float*)d_in[5];
  const float* bk  = (const float*)d_in[6];
  const float* Wv  = (const float*)d_in[7];
  const float* bv  = (const float*)d_in[8];
  const float* Ws  = (const float*)d_in[9];
  const float* bs  = (const float*)d_in[10];
  const float* Wa1 = (const float*)d_in[11];
  const float* ba1 = (const float*)d_in[12];
  const float* Wa2 = (const float*)d_in[13];
  const float* ba2 = (const float*)d_in[14];
  const float* Wc  = (const float*)d_in[15];
  const float* bc  = (const float*)d_in[16];
  float* out = (float*)d_out;

  const int n  = in_sizes[0] / 512;   // 20000
  const int ne = in_sizes[1] / 2;     // 320000

  char* ws = (char*)d_ws;
  size_t off = 0;
  auto take = [&](size_t bytes){ size_t r = off; off += (bytes + 255) & ~(size_t)255; return r; };
  unsigned short* wcatT  = (unsigned short*)(ws + take((size_t)1024 * 512 * 2));
  float*          bcat   = (float*)(ws + take(1024 * 4));
  unsigned short* xbf    = (unsigned short*)(ws + take((size_t)n * 512 * 2));
  unsigned short* qbf    = (unsigned short*)(ws + take((size_t)n * 256 * 2));
  unsigned short* sbf    = (unsigned short*)(ws + take((size_t)n * 256 * 2));
  unsigned char*  kv8    = (unsigned char*)(ws + take((size_t)n * 512));
  unsigned short* hbf    = (unsigned short*)(ws + take((size_t)n * 256 * 2));
  unsigned short* wa1T   = (unsigned short*)(ws + take((size_t)256 * 256 * 2));
  float*          s2     = (float*)(ws + take((size_t)n * 2 * 4));
  size_t zoff = off;
  int*            deg    = (int*)(ws + take((size_t)n * 4));
  int*            cursor = (int*)(ws + take((size_t)n * 4));
  float*          Mbuf   = (float*)(ws + take(512 * 4));
  size_t zlen = off - zoff;
  int*            rowst  = (int*)(ws + take((size_t)(n + 1) * 4));
  int*            csrsrc = (int*)(ws + take((size_t)ne * 4));
  float*          red    = (float*)(ws + take(4 * 4));

  hipMemsetAsync(ws + zoff, 0, zlen, stream);

  pack_weights<<<(1024 * 512 + 255) / 256, 256, 0, stream>>>(Wq, Wk, Wv, Ws, bq, bk, bv, bs, wcatT, bcat);
  pack_wa1<<<256, 256, 0, stream>>>(Wa1, wa1T);
  convert_x<<<(n * 64 + 255) / 256, 256, 0, stream>>>(x, xbf, n * 64);
  const int mblocks = (n + 127) / 128;
  gemm_qkvs<<<8 * mblocks, 256, 0, stream>>>(xbf, wcatT, bcat, qbf, sbf, kv8, n, mblocks);
  degree_hist<<<(ne + 255) / 256, 256, 0, stream>>>(ei, deg, ne);
  scan_deg<<<1, 1024, 0, stream>>>(deg, rowst, n, ne);
  scatter_edges<<<(ne + 255) / 256, 256, 0, stream>>>(ei, rowst, cursor, csrsrc, ne);
  edge_attn<<<(n + 15) / 16, 256, 0, stream>>>(qbf, sbf, kv8, rowst, csrsrc, hbf, n);
  mlp_mfma<<<(n + 63) / 64, 256, 0, stream>>>(hbf, wa1T, ba1, Wa2, ba2, s2, n);
  col_reduce<<<1, 1024, 0, stream>>>(s2, red, n);
  attn_M<<<(n + 255) / 256, 256, 0, stream>>>(s2, red, hbf, lab, Mbuf, out + 4, n);
  final_k<<<1, 256, 0, stream>>>(Mbuf, Wc, bc, out);
  (void)ws_size; (void)out_size; (void)n_in;
}

// Round 8
// 197.552 us; speedup vs baseline: 1.1841x; 1.0707x over previous
//
#include <hip/hip_runtime.h>
#include <hip/hip_bf16.h>
#include <math.h>

typedef float f32x4_t __attribute__((ext_vector_type(4)));
typedef float f32x2_t __attribute__((ext_vector_type(2)));
typedef __bf16 bf16x8_t __attribute__((ext_vector_type(8)));

__device__ __forceinline__ float bf2f(unsigned int u){
  union { float f; unsigned int i; } x; x.i = u << 16; return x.f;
}
__device__ __forceinline__ unsigned short f2bf(float f){
  unsigned int x = __float_as_uint(f);
  unsigned int r = (x + 0x7fffu + ((x >> 16) & 1u)) >> 16;
  return (unsigned short)r;
}
__device__ __forceinline__ unsigned int pk2bf(float a, float b){
  return (unsigned int)f2bf(a) | ((unsigned int)f2bf(b) << 16);
}
// LDS unit swizzle: r = row (0..127), 2-bit XOR applied to 16B-unit index
__device__ __forceinline__ int swz4(int r){ return (r ^ (r >> 2) ^ (r >> 4)) & 3; }

// unpack 8 bf16 (uint4) -> 8 floats, scaled
__device__ __forceinline__ void unp8s(uint4 w, float* f, float s){
  f[0] = bf2f(w.x & 0xffffu) * s; f[1] = bf2f(w.x >> 16) * s;
  f[2] = bf2f(w.y & 0xffffu) * s; f[3] = bf2f(w.y >> 16) * s;
  f[4] = bf2f(w.z & 0xffffu) * s; f[5] = bf2f(w.z >> 16) * s;
  f[6] = bf2f(w.w & 0xffffu) * s; f[7] = bf2f(w.w >> 16) * s;
}
// unpack 4 fp8 e4m3 (one u32) -> 4 floats (HW cvt)
__device__ __forceinline__ void unpf8(unsigned int w, float* f){
  f32x2_t lo = __builtin_amdgcn_cvt_pk_f32_fp8(w, false);
  f32x2_t hi = __builtin_amdgcn_cvt_pk_f32_fp8(w, true);
  f[0] = lo[0]; f[1] = lo[1]; f[2] = hi[0]; f[3] = hi[1];
}

#define GLOAD16(gsrc, ldst) \
  __builtin_amdgcn_global_load_lds((const __attribute__((address_space(1))) unsigned int*)(gsrc), \
                                   (__attribute__((address_space(3))) unsigned int*)(ldst), 16, 0, 0)

// ---------------- K0: fused prep — pack_weights | pack_wa1 | convert_x | degree_hist
// (all independent; one launch, co-scheduled)
__global__ void prep(const float* __restrict__ x,
                     const float* __restrict__ Wq, const float* __restrict__ Wk,
                     const float* __restrict__ Wv, const float* __restrict__ Ws,
                     const float* __restrict__ bq, const float* __restrict__ bk,
                     const float* __restrict__ bv, const float* __restrict__ bs,
                     const float* __restrict__ Wa1, const int* __restrict__ ei,
                     unsigned short* __restrict__ xbf, unsigned short* __restrict__ wcatT,
                     float* __restrict__ bcat, unsigned short* __restrict__ wa1T,
                     int* __restrict__ deg, int n, int ne, int nbcv){
  const int b = blockIdx.x, tid = threadIdx.x;
  if (b < 2048){
    // pack weights -> wcatT bf16 [1024][512] PRE-SWIZZLED, biases -> bcat
    int idx = b * 256 + tid;
    int c = idx >> 9, k = idx & 511;
    int sel = c >> 8, cc = c & 255;
    const float* W = (sel == 0) ? Wq : (sel == 1) ? Wk : (sel == 2) ? Wv : Ws;
    int p = ((k >> 3) & 3) ^ swz4(c & 127);
    int dst = c * 512 + (k & ~31) + p * 8 + (k & 7);
    wcatT[dst] = f2bf(W[k * 256 + cc]);
    if (idx < 1024){
      int sel2 = idx >> 8, cc2 = idx & 255;
      const float* B = (sel2 == 0) ? bq : (sel2 == 1) ? bk : (sel2 == 2) ? bv : bs;
      bcat[idx] = B[cc2];
    }
  } else if (b < 2304){
    // pack Wa1^T -> bf16 [256 cols][256 k]
    int idx = (b - 2048) * 256 + tid;
    int c = idx >> 8, k = idx & 255;
    wa1T[idx] = f2bf(Wa1[k * 256 + c]);
  } else if (b < 2304 + nbcv){
    // convert x fp32 -> xbf bf16 PRE-SWIZZLED (same image layout as wcatT)
    int idx = (b - 2304) * 256 + tid;
    if (idx < n * 64){
      int node = idx >> 6, un = idx & 63;
      int k0 = (un >> 2) * 32, u = un & 3;
      const float* src = x + (size_t)node * 512 + k0 + u * 8;
      float4 f0 = *reinterpret_cast<const float4*>(src);
      float4 f1 = *reinterpret_cast<const float4*>(src + 4);
      uint4 o;
      o.x = pk2bf(f0.x, f0.y); o.y = pk2bf(f0.z, f0.w);
      o.z = pk2bf(f1.x, f1.y); o.w = pk2bf(f1.z, f1.w);
      int p = u ^ swz4(node & 127);
      *reinterpret_cast<uint4*>(xbf + (size_t)node * 512 + k0 + p * 8) = o;
    }
  } else {
    // degree histogram
    int i = (b - 2304 - nbcv) * 256 + tid;
    if (i < ne) atomicAdd(&deg[ei[ne + i]], 1);
  }
}

// ---------------- K3: QKVS GEMM: triple-buffered async gload_lds (pre-swizzled images),
// counted vmcnt(8) + raw barriers, XCD-swizzled grid, swapped-operand MFMA,
// bank-uniform LDS-staged epilogue. Writes q/s bf16 + k/v fp8.
__global__ __launch_bounds__(256) void gemm_qkvs(const unsigned short* __restrict__ xbf,
                                                 const unsigned short* __restrict__ wcatT,
                                                 const float* __restrict__ bcat,
                                                 unsigned short* __restrict__ qbf,
                                                 unsigned short* __restrict__ sbf,
                                                 unsigned char* __restrict__ kv8,
                                                 int n_nodes, int mblocks){
  __shared__ __align__(16) unsigned char smem[49152];    // 3 x (As 8KB + Bs 8KB); epilogue reuses
  const int tid = threadIdx.x;
  const int lane = tid & 63, wave = tid >> 6;
  const int wm = wave >> 1, wn = wave & 1;
  const int g = (blockIdx.x & 7) * mblocks + (blockIdx.x >> 3);
  const int m_blk = g >> 3, n_blk = g & 7;
  const int m0 = m_blk * 128, n0 = n_blk * 128;
  const int lrow = lane >> 2;
  const int lcol = (lane & 3) * 8;
  const int rA0 = min(m0 + wave * 16 + lrow, n_nodes - 1);
  const int rA1 = min(m0 + (wave + 4) * 16 + lrow, n_nodes - 1);
  const int rB0 = n0 + wave * 16 + lrow;
  const int rB1 = rB0 + 64;
  const int r = lane & 15, q4 = lane >> 4;
  const unsigned short* aG0 = xbf   + (size_t)rA0 * 512 + lcol;
  const unsigned short* aG1 = xbf   + (size_t)rA1 * 512 + lcol;
  const unsigned short* bG0 = wcatT + (size_t)rB0 * 512 + lcol;
  const unsigned short* bG1 = wcatT + (size_t)rB1 * 512 + lcol;
  // swizzled fragment read offsets (shorts within a tile)
  int aoff[4], boff[4];
  #pragma unroll
  for (int mi = 0; mi < 4; mi++){ int rr = wm * 64 + mi * 16 + r; aoff[mi] = rr * 32 + ((q4 ^ swz4(rr)) * 8); }
  #pragma unroll
  for (int ni = 0; ni < 4; ni++){ int rb = wn * 64 + ni * 16 + r; boff[ni] = rb * 32 + ((q4 ^ swz4(rb)) * 8); }
  f32x4_t acc[4][4] = {};
#define STAGE(base, k0) { \
    unsigned short* As_ = (unsigned short*)(smem + (base)); \
    unsigned short* Bs_ = (unsigned short*)(smem + (base) + 8192); \
    GLOAD16(aG0 + (k0), &As_[wave * 512]); \
    GLOAD16(aG1 + (k0), &As_[(wave + 4) * 512]); \
    GLOAD16(bG0 + (k0), &Bs_[wave * 512]); \
    GLOAD16(bG1 + (k0), &Bs_[(wave + 4) * 512]); \
  }
  STAGE(0, 0);
  STAGE(16384, 32);
  int cbase = 0;       // buffer holding tile t
  int sbase = 32768;   // buffer receiving tile t+2
  for (int t = 0; t < 16; t++){
    if (t + 2 < 16){
      STAGE(sbase, (t + 2) * 32);
      asm volatile("s_waitcnt vmcnt(8)" ::: "memory");   // tiles t+1,t+2 stay in flight
    } else if (t + 1 < 16){
      asm volatile("s_waitcnt vmcnt(4)" ::: "memory");
    } else {
      asm volatile("s_waitcnt vmcnt(0)" ::: "memory");
    }
    __builtin_amdgcn_s_barrier();
    asm volatile("" ::: "memory");
    const unsigned short* As = (const unsigned short*)(smem + cbase);
    const unsigned short* Bs = (const unsigned short*)(smem + cbase + 8192);
    bf16x8_t a[4], b[4];
    #pragma unroll
    for (int mi = 0; mi < 4; mi++) a[mi] = *reinterpret_cast<const bf16x8_t*>(&As[aoff[mi]]);
    #pragma unroll
    for (int ni = 0; ni < 4; ni++) b[ni] = *reinterpret_cast<const bf16x8_t*>(&Bs[boff[ni]]);
    // swapped operands: lane holds output row m = r, 4 consecutive n-cols (q4*4+j)
    #pragma unroll
    for (int mi = 0; mi < 4; mi++)
      #pragma unroll
      for (int ni = 0; ni < 4; ni++)
        acc[mi][ni] = __builtin_amdgcn_mfma_f32_16x16x32_bf16(b[ni], a[mi], acc[mi][ni], 0, 0, 0);
    __builtin_amdgcn_s_barrier();                         // all waves done reading buf[t]
    asm volatile("" ::: "memory");
    cbase += 16384; if (cbase == 49152) cbase = 0;
    sbase += 16384; if (sbase == 49152) sbase = 0;
  }
#undef STAGE
  // ---- epilogue: 2 chunks of 64 rows, LDS-staged with bank-uniform strides, coalesced stores ----
  const bool isQ = (n_blk < 2), isS = (n_blk >= 6);
  if (isQ || isS){
    unsigned short* St = (unsigned short*)smem;   // [64][152] bf16
    unsigned short* outp = isQ ? qbf : sbf;
    const int colhalf = isQ ? n_blk : (n_blk - 6);
    #pragma unroll
    for (int ch = 0; ch < 2; ch++){
      if (wm == ch){
        #pragma unroll
        for (int mi = 0; mi < 4; mi++){
          #pragma unroll
          for (int ni = 0; ni < 4; ni++){
            int mloc = mi * 16 + r;
            int nl = wn * 64 + ni * 16 + q4 * 4;
            float4 bb = *reinterpret_cast<const float4*>(&bcat[n0 + nl]);
            uint2 w;
            w.x = pk2bf(acc[mi][ni][0] + bb.x, acc[mi][ni][1] + bb.y);
            w.y = pk2bf(acc[mi][ni][2] + bb.z, acc[mi][ni][3] + bb.w);
            *reinterpret_cast<uint2*>(&St[mloc * 152 + nl]) = w;
          }
        }
      }
      __syncthreads();
      #pragma unroll
      for (int it = 0; it < 4; it++){
        int u = it * 256 + tid;
        int row = u >> 4, seg = (u & 15) * 8;
        int node = m0 + ch * 64 + row;
        if (node < n_nodes){
          uint4 v = *reinterpret_cast<const uint4*>(&St[row * 152 + seg]);
          *reinterpret_cast<uint4*>(outp + (size_t)node * 256 + colhalf * 128 + seg) = v;
        }
      }
      __syncthreads();
    }
  } else {
    unsigned char* St8 = smem;                    // [64][144] fp8
    #pragma unroll
    for (int ch = 0; ch < 2; ch++){
      if (wm == ch){
        #pragma unroll
        for (int mi = 0; mi < 4; mi++){
          #pragma unroll
          for (int ni = 0; ni < 4; ni++){
            int mloc = mi * 16 + r;
            int nl = wn * 64 + ni * 16 + q4 * 4;
            float4 bb = *reinterpret_cast<const float4*>(&bcat[n0 + nl]);
            int u = 0;
            u = __builtin_amdgcn_cvt_pk_fp8_f32(acc[mi][ni][0] + bb.x, acc[mi][ni][1] + bb.y, u, false);
            u = __builtin_amdgcn_cvt_pk_fp8_f32(acc[mi][ni][2] + bb.z, acc[mi][ni][3] + bb.w, u, true);
            *reinterpret_cast<unsigned int*>(&St8[mloc * 144 + nl]) = (unsigned int)u;
          }
        }
      }
      __syncthreads();
      #pragma unroll
      for (int it = 0; it < 2; it++){
        int u = it * 256 + tid;
        int row = u >> 3, seg = (u & 7) * 16;
        int node = m0 + ch * 64 + row;
        if (node < n_nodes){
          uint4 v = *reinterpret_cast<const uint4*>(&St8[row * 144 + seg]);
          *reinterpret_cast<uint4*>(kv8 + (size_t)node * 512 + (n_blk - 2) * 128 + seg) = v;
        }
      }
      __syncthreads();
    }
  }
}

// ---------------- K5: exclusive scan, single block, 2-pass blocked
__global__ void scan_deg(const int* __restrict__ deg, int* __restrict__ rowstart, int n, int ne){
  __shared__ int sm[1024];
  int tid = threadIdx.x;
  int per = (n + 1023) / 1024;
  int start = tid * per;
  int sum = 0;
  for (int i = 0; i < per; i++){
    int idx = start + i;
    sum += (idx < n) ? deg[idx] : 0;
  }
  sm[tid] = sum; __syncthreads();
  for (int off = 1; off < 1024; off <<= 1){
    int t = (tid >= off) ? sm[tid - off] : 0;
    __syncthreads();
    sm[tid] += t;
    __syncthreads();
  }
  int run = sm[tid] - sum;
  for (int i = 0; i < per; i++){
    int idx = start + i;
    if (idx < n){
      rowstart[idx] = run;
      run += deg[idx];
    }
  }
  if (tid == 0) rowstart[n] = ne;
}

// ---------------- K6: scatter edges into CSR (stores src*512 byte-offset)
__global__ void scatter_edges(const int* __restrict__ ei, const int* __restrict__ rowstart,
                              int* __restrict__ cursor, int* __restrict__ csrsrc, int ne){
  int i = blockIdx.x * 256 + threadIdx.x;
  if (i < ne){
    int d = ei[ne + i];
    int pos = atomicAdd(&cursor[d], 1);
    csrsrc[rowstart[d] + pos] = ei[i] << 9;
  }
}

// ---------------- K7: per-dst online-softmax aggregation
// fp8 K/V, 16 lanes/edge, 4 nodes/wave, 2-edge-wide update (halves serial chain), pair prefetch
__global__ __launch_bounds__(256) void edge_attn(const unsigned short* __restrict__ qbf,
                                                 const unsigned short* __restrict__ sbf,
                                                 const unsigned char* __restrict__ kv8,
                                                 const int* __restrict__ rowstart,
                                                 const int* __restrict__ csrsrc,
                                                 unsigned short* __restrict__ hbf, int n_nodes){
  const int tid = threadIdx.x;
  const int lane = tid & 63, wave = tid >> 6;
  const int g = lane >> 4, t = lane & 15;
  const int node = blockIdx.x * 16 + wave * 4 + g;
  const bool active = node < n_nodes;
  const int nd = active ? node : 0;
  const float qs = 0.0625f * 1.44269504088896340736f;  // (1/sqrt(256)) * log2(e)
  float q[16];
  {
    const unsigned short* qp = qbf + (size_t)nd * 256 + t * 16;
    uint4 w0 = *reinterpret_cast<const uint4*>(qp);
    uint4 w1 = *reinterpret_cast<const uint4*>(qp + 8);
    unp8s(w0, q, qs); unp8s(w1, q + 8, qs);
  }
  int rs = rowstart[nd];
  int re = active ? rowstart[nd + 1] : rs;
  float m = -1e30f, den = 0.f;
  float acc[16];
  #pragma unroll
  for (int j = 0; j < 16; j++) acc[j] = 0.f;
  uint4 kA = make_uint4(0,0,0,0), vA = kA, kB = kA, vB = kA;
  if (rs < re){
    const unsigned char* p1 = kv8 + (size_t)csrsrc[rs] + t * 16;
    kA = *reinterpret_cast<const uint4*>(p1);
    vA = *reinterpret_cast<const uint4*>(p1 + 256);
    if (rs + 1 < re){
      const unsigned char* p2 = kv8 + (size_t)csrsrc[rs + 1] + t * 16;
      kB = *reinterpret_cast<const uint4*>(p2);
      vB = *reinterpret_cast<const uint4*>(p2 + 256);
    }
  }
  for (int i = rs; i < re; i += 2){
    uint4 k1 = kA, v1 = vA, k2 = kB, v2 = vB;
    const bool has2 = (i + 1 < re);
    if (i + 2 < re){            // prefetch next pair
      const unsigned char* p1 = kv8 + (size_t)csrsrc[i + 2] + t * 16;
      kA = *reinterpret_cast<const uint4*>(p1);
      vA = *reinterpret_cast<const uint4*>(p1 + 256);
      if (i + 3 < re){
        const unsigned char* p2 = kv8 + (size_t)csrsrc[i + 3] + t * 16;
        kB = *reinterpret_cast<const uint4*>(p2);
        vB = *reinterpret_cast<const uint4*>(p2 + 256);
      }
    }
    float kf1[16], kf2[16];
    unpf8(k1.x, kf1); unpf8(k1.y, kf1 + 4); unpf8(k1.z, kf1 + 8); unpf8(k1.w, kf1 + 12);
    unpf8(k2.x, kf2); unpf8(k2.y, kf2 + 4); unpf8(k2.z, kf2 + 8); unpf8(k2.w, kf2 + 12);
    float s1 = 0.f, s2 = 0.f;
    #pragma unroll
    for (int j = 0; j < 16; j++){ s1 = fmaf(q[j], kf1[j], s1); s2 = fmaf(q[j], kf2[j], s2); }
    s1 += __shfl_xor(s1, 1); s2 += __shfl_xor(s2, 1);
    s1 += __shfl_xor(s1, 2); s2 += __shfl_xor(s2, 2);
    s1 += __shfl_xor(s1, 4); s2 += __shfl_xor(s2, 4);
    s1 += __shfl_xor(s1, 8); s2 += __shfl_xor(s2, 8);
    if (!has2) s2 = -1e30f;     // e2 -> 0, v2 contribution vanishes
    float vf1[16], vf2[16];
    unpf8(v1.x, vf1); unpf8(v1.y, vf1 + 4); unpf8(v1.z, vf1 + 8); unpf8(v1.w, vf1 + 12);
    unpf8(v2.x, vf2); unpf8(v2.y, vf2 + 4); unpf8(v2.z, vf2 + 8); unpf8(v2.w, vf2 + 12);
    float mn = fmaxf(m, fmaxf(s1, s2));
    float sc = exp2f(m - mn);
    float e1 = exp2f(s1 - mn);
    float e2 = exp2f(s2 - mn);
    den = den * sc + e1 + e2;
    #pragma unroll
    for (int j = 0; j < 16; j++)
      acc[j] = fmaf(acc[j], sc, fmaf(e1, vf1[j], e2 * vf2[j]));
    m = mn;
  }
  float inv = (den > 0.f) ? 1.f / den : 0.f;
  const unsigned short* sp = sbf + (size_t)nd * 256 + t * 16;
  uint4 s0 = *reinterpret_cast<const uint4*>(sp);
  uint4 s1v = *reinterpret_cast<const uint4*>(sp + 8);
  float sf[16]; unp8s(s0, sf, 1.0f); unp8s(s1v, sf + 8, 1.0f);
  const float inv_sqrt2 = 0.70710678118654752f;
  unsigned int o[8];
  #pragma unroll
  for (int j = 0; j < 8; j++){
    float h0 = acc[2 * j] * inv + sf[2 * j];
    float h1 = acc[2 * j + 1] * inv + sf[2 * j + 1];
    h0 = 0.5f * h0 * (1.f + erff(h0 * inv_sqrt2));
    h1 = 0.5f * h1 * (1.f + erff(h1 * inv_sqrt2));
    o[j] = (unsigned int)f2bf(h0) | ((unsigned int)f2bf(h1) << 16);
  }
  if (active){
    uint4* dst = reinterpret_cast<uint4*>(hbf + (size_t)node * 256 + t * 16);
    dst[0] = make_uint4(o[0], o[1], o[2], o[3]);
    dst[1] = make_uint4(o[4], o[5], o[6], o[7]);
  }
}

// ---------------- K8: s2[n][2] = tanh(hbf@Wa1 + ba1)@Wa2 + ba2  (bf16 MFMA)
__global__ __launch_bounds__(256) void mlp_mfma(const unsigned short* __restrict__ hbf,
                                                const unsigned short* __restrict__ wa1T,
                                                const float* __restrict__ ba1,
                                                const float* __restrict__ Wa2,
                                                const float* __restrict__ ba2,
                                                float* __restrict__ s2, int n_nodes){
  __shared__ __align__(16) unsigned short As[64 * 72];
  __shared__ float s2s[64][2];
  const int tid = threadIdx.x;
  const int lane = tid & 63, wave = tid >> 6;
  const int m0 = blockIdx.x * 64;
  const int c0 = wave * 64;
  const int r = lane & 15, rg = (lane >> 4) * 4;
  if (tid < 128) s2s[tid >> 1][tid & 1] = 0.f;
  f32x4_t acc[4][4] = {};
  for (int k0 = 0; k0 < 256; k0 += 64){
    int arow = tid >> 2, akc = (tid & 3) * 16;
    uint4 a0v = make_uint4(0,0,0,0), a1v = make_uint4(0,0,0,0);
    if (m0 + arow < n_nodes){
      const unsigned short* src = hbf + (size_t)(m0 + arow) * 256 + k0 + akc;
      a0v = *reinterpret_cast<const uint4*>(src);
      a1v = *reinterpret_cast<const uint4*>(src + 8);
    }
    *reinterpret_cast<uint4*>(&As[arow * 72 + akc]) = a0v;
    *reinterpret_cast<uint4*>(&As[arow * 72 + akc + 8]) = a1v;
    __syncthreads();
    #pragma unroll
    for (int kk = 0; kk < 2; kk++){
      int kg = kk * 32 + (lane >> 4) * 8;
      bf16x8_t a[4], b[4];
      #pragma unroll
      for (int mi = 0; mi < 4; mi++)
        a[mi] = *reinterpret_cast<const bf16x8_t*>(&As[(mi * 16 + r) * 72 + kg]);
      #pragma unroll
      for (int ni = 0; ni < 4; ni++)
        b[ni] = *reinterpret_cast<const bf16x8_t*>(wa1T + (size_t)(c0 + ni * 16 + r) * 256 + k0 + kg);
      #pragma unroll
      for (int mi = 0; mi < 4; mi++)
        #pragma unroll
        for (int ni = 0; ni < 4; ni++)
          acc[mi][ni] = __builtin_amdgcn_mfma_f32_16x16x32_bf16(a[mi], b[ni], acc[mi][ni], 0, 0, 0);
    }
    __syncthreads();
  }
  float w20[4], w21[4], b1c[4];
  #pragma unroll
  for (int ni = 0; ni < 4; ni++){
    int col = c0 + ni * 16 + r;
    w20[ni] = Wa2[col * 2]; w21[ni] = Wa2[col * 2 + 1]; b1c[ni] = ba1[col];
  }
  #pragma unroll
  for (int mi = 0; mi < 4; mi++){
    #pragma unroll
    for (int j = 0; j < 4; j++){
      float t0 = 0.f, t1 = 0.f;
      #pragma unroll
      for (int ni = 0; ni < 4; ni++){
        float t = tanhf(acc[mi][ni][j] + b1c[ni]);
        t0 += t * w20[ni]; t1 += t * w21[ni];
      }
      t0 += __shfl_xor(t0, 1); t0 += __shfl_xor(t0, 2);
      t0 += __shfl_xor(t0, 4); t0 += __shfl_xor(t0, 8);
      t1 += __shfl_xor(t1, 1); t1 += __shfl_xor(t1, 2);
      t1 += __shfl_xor(t1, 4); t1 += __shfl_xor(t1, 8);
      if (r == 0){
        int row = mi * 16 + rg + j;
        atomicAdd(&s2s[row][0], t0);
        atomicAdd(&s2s[row][1], t1);
      }
    }
  }
  __syncthreads();
  if (tid < 128){
    int row = tid >> 1, c = tid & 1;
    int node = m0 + row;
    if (node < n_nodes) s2[node * 2 + c] = s2s[row][c] + ba2[c];
  }
}

// ---------------- K9: column max + exp-sum over n (single block)
__global__ void col_reduce(const float* __restrict__ s2, float* __restrict__ red, int n){
  __shared__ float sm[1024];
  __shared__ float mshare[2];
  int tid = threadIdx.x;
  float mx0 = -INFINITY, mx1 = -INFINITY;
  for (int i = tid; i < n; i += 1024){
    mx0 = fmaxf(mx0, s2[2 * i]);
    mx1 = fmaxf(mx1, s2[2 * i + 1]);
  }
  sm[tid] = mx0; __syncthreads();
  for (int off = 512; off > 0; off >>= 1){
    if (tid < off) sm[tid] = fmaxf(sm[tid], sm[tid + off]);
    __syncthreads();
  }
  if (tid == 0) mshare[0] = sm[0];
  __syncthreads();
  sm[tid] = mx1; __syncthreads();
  for (int off = 512; off > 0; off >>= 1){
    if (tid < off) sm[tid] = fmaxf(sm[tid], sm[tid + off]);
    __syncthreads();
  }
  if (tid == 0) mshare[1] = sm[0];
  __syncthreads();
  float m0 = mshare[0], m1 = mshare[1];
  float s0 = 0.f, s1 = 0.f;
  for (int i = tid; i < n; i += 1024){
    s0 += expf(s2[2 * i] - m0);
    s1 += expf(s2[2 * i + 1] - m1);
  }
  sm[tid] = s0; __syncthreads();
  for (int off = 512; off > 0; off >>= 1){
    if (tid < off) sm[tid] += sm[tid + off];
    __syncthreads();
  }
  float den0 = sm[0];
  __syncthreads();
  sm[tid] = s1; __syncthreads();
  for (int off = 512; off > 0; off >>= 1){
    if (tid < off) sm[tid] += sm[tid + off];
    __syncthreads();
  }
  if (tid == 0){
    red[0] = m0; red[1] = m1; red[2] = den0; red[3] = sm[0];
  }
}

// ---------------- K10: attn, A output, M partial accumulation (reads bf16 h)
__global__ __launch_bounds__(256) void attn_M(const float* __restrict__ s2, const float* __restrict__ red,
                                              const unsigned short* __restrict__ hbf, const int* __restrict__ label,
                                              float* __restrict__ Mbuf, float* __restrict__ outA, int n){
  __shared__ float a0s[256], a1s[256];
  int tid = threadIdx.x;
  int n0 = blockIdx.x * 256;
  int node = n0 + tid;
  float m0 = red[0], m1 = red[1];
  float i0 = 1.f / red[2], i1 = 1.f / red[3];
  float a0 = 0.f, a1 = 0.f;
  if (node < n){
    a0 = expf(s2[2 * node] - m0) * i0;
    a1 = expf(s2[2 * node + 1] - m1) * i1;
    outA[node] = (label[0] == 0) ? a0 : a1;
  }
  a0s[tid] = a0; a1s[tid] = a1;
  __syncthreads();
  int d = tid;
  float M0 = 0.f, M1 = 0.f;
  int cnt = min(256, n - n0);
  for (int i = 0; i < cnt; i++){
    float hv = bf2f((unsigned int)hbf[(size_t)(n0 + i) * 256 + d]);
    M0 += a0s[i] * hv;
    M1 += a1s[i] * hv;
  }
  atomicAdd(&Mbuf[d], M0);
  atomicAdd(&Mbuf[256 + d], M1);
}

// ---------------- K11: logits + Y_prob
__global__ void final_k(const float* __restrict__ Mbuf, const float* __restrict__ Wc,
                        const float* __restrict__ bc, float* __restrict__ out){
  __shared__ float sm[256];
  __shared__ float l0s;
  int tid = threadIdx.x;
  float p0 = Mbuf[tid] * Wc[tid];
  float p1 = Mbuf[256 + tid] * Wc[256 + tid];
  sm[tid] = p0; __syncthreads();
  for (int off = 128; off > 0; off >>= 1){
    if (tid < off) sm[tid] += sm[tid + off];
    __syncthreads();
  }
  if (tid == 0) l0s = sm[0];
  __syncthreads();
  sm[tid] = p1; __syncthreads();
  for (int off = 128; off > 0; off >>= 1){
    if (tid < off) sm[tid] += sm[tid + off];
    __syncthreads();
  }
  if (tid == 0){
    float l0 = l0s + bc[0];
    float l1 = sm[0] + bc[1];
    out[0] = l0; out[1] = l1;
    float mx = fmaxf(l0, l1);
    float e0 = expf(l0 - mx), e1 = expf(l1 - mx);
    float inv = 1.f / (e0 + e1);
    out[2] = e0 * inv; out[3] = e1 * inv;
  }
}

extern "C" void kernel_launch(void* const* d_in, const int* in_sizes, int n_in,
                              void* d_out, int out_size, void* d_ws, size_t ws_size,
                              hipStream_t stream) {
  const float* x   = (const float*)d_in[0];
  const int*   ei  = (const int*)d_in[1];
  const int*   lab = (const int*)d_in[2];
  const float* Wq  = (const float*)d_in[3];
  const float* bq  = (const float*)d_in[4];
  const float* Wk  = (const float*)d_in[5];
  const float* bk  = (const float*)d_in[6];
  const float* Wv  = (const float*)d_in[7];
  const float* bv  = (const float*)d_in[8];
  const float* Ws  = (const float*)d_in[9];
  const float* bs  = (const float*)d_in[10];
  const float* Wa1 = (const float*)d_in[11];
  const float* ba1 = (const float*)d_in[12];
  const float* Wa2 = (const float*)d_in[13];
  const float* ba2 = (const float*)d_in[14];
  const float* Wc  = (const float*)d_in[15];
  const float* bc  = (const float*)d_in[16];
  float* out = (float*)d_out;

  const int n  = in_sizes[0] / 512;   // 20000
  const int ne = in_sizes[1] / 2;     // 320000

  char* ws = (char*)d_ws;
  size_t off = 0;
  auto take = [&](size_t bytes){ size_t r = off; off += (bytes + 255) & ~(size_t)255; return r; };
  unsigned short* wcatT  = (unsigned short*)(ws + take((size_t)1024 * 512 * 2));
  float*          bcat   = (float*)(ws + take(1024 * 4));
  unsigned short* xbf    = (unsigned short*)(ws + take((size_t)n * 512 * 2));
  unsigned short* qbf    = (unsigned short*)(ws + take((size_t)n * 256 * 2));
  unsigned short* sbf    = (unsigned short*)(ws + take((size_t)n * 256 * 2));
  unsigned char*  kv8    = (unsigned char*)(ws + take((size_t)n * 512));
  unsigned short* hbf    = (unsigned short*)(ws + take((size_t)n * 256 * 2));
  unsigned short* wa1T   = (unsigned short*)(ws + take((size_t)256 * 256 * 2));
  float*          s2     = (float*)(ws + take((size_t)n * 2 * 4));
  size_t zoff = off;
  int*            deg    = (int*)(ws + take((size_t)n * 4));
  int*            cursor = (int*)(ws + take((size_t)n * 4));
  float*          Mbuf   = (float*)(ws + take(512 * 4));
  size_t zlen = off - zoff;
  int*            rowst  = (int*)(ws + take((size_t)(n + 1) * 4));
  int*            csrsrc = (int*)(ws + take((size_t)ne * 4));
  float*          red    = (float*)(ws + take(4 * 4));

  hipMemsetAsync(ws + zoff, 0, zlen, stream);

  const int nbcv = (n * 64 + 255) / 256;
  const int nbdh = (ne + 255) / 256;
  prep<<<2304 + nbcv + nbdh, 256, 0, stream>>>(x, Wq, Wk, Wv, Ws, bq, bk, bv, bs, Wa1, ei,
                                               xbf, wcatT, bcat, wa1T, deg, n, ne, nbcv);
  const int mblocks = (n + 127) / 128;
  gemm_qkvs<<<8 * mblocks, 256, 0, stream>>>(xbf, wcatT, bcat, qbf, sbf, kv8, n, mblocks);
  scan_deg<<<1, 1024, 0, stream>>>(deg, rowst, n, ne);
  scatter_edges<<<(ne + 255) / 256, 256, 0, stream>>>(ei, rowst, cursor, csrsrc, ne);
  edge_attn<<<(n + 15) / 16, 256, 0, stream>>>(qbf, sbf, kv8, rowst, csrsrc, hbf, n);
  mlp_mfma<<<(n + 63) / 64, 256, 0, stream>>>(hbf, wa1T, ba1, Wa2, ba2, s2, n);
  col_reduce<<<1, 1024, 0, stream>>>(s2, red, n);
  attn_M<<<(n + 255) / 256, 256, 0, stream>>>(s2, red, hbf, lab, Mbuf, out + 4, n);
  final_k<<<1, 256, 0, stream>>>(Mbuf, Wc, bc, out);
  (void)ws_size; (void)out_size; (void)n_in;
}

// Round 9
// 193.078 us; speedup vs baseline: 1.2115x; 1.0232x over previous
//
#include <hip/hip_runtime.h>
#include <hip/hip_bf16.h>
#include <math.h>

typedef float f32x4_t __attribute__((ext_vector_type(4)));
typedef float f32x2_t __attribute__((ext_vector_type(2)));
typedef __bf16 bf16x8_t __attribute__((ext_vector_type(8)));

__device__ __forceinline__ float bf2f(unsigned int u){
  union { float f; unsigned int i; } x; x.i = u << 16; return x.f;
}
__device__ __forceinline__ unsigned short f2bf(float f){
  unsigned int x = __float_as_uint(f);
  unsigned int r = (x + 0x7fffu + ((x >> 16) & 1u)) >> 16;
  return (unsigned short)r;
}
__device__ __forceinline__ unsigned int pk2bf(float a, float b){
  return (unsigned int)f2bf(a) | ((unsigned int)f2bf(b) << 16);
}
// LDS unit swizzle: r = row (0..127), 2-bit XOR applied to 16B-unit index
__device__ __forceinline__ int swz4(int r){ return (r ^ (r >> 2) ^ (r >> 4)) & 3; }

// unpack 8 bf16 (uint4) -> 8 floats, scaled
__device__ __forceinline__ void unp8s(uint4 w, float* f, float s){
  f[0] = bf2f(w.x & 0xffffu) * s; f[1] = bf2f(w.x >> 16) * s;
  f[2] = bf2f(w.y & 0xffffu) * s; f[3] = bf2f(w.y >> 16) * s;
  f[4] = bf2f(w.z & 0xffffu) * s; f[5] = bf2f(w.z >> 16) * s;
  f[6] = bf2f(w.w & 0xffffu) * s; f[7] = bf2f(w.w >> 16) * s;
}
// unpack 4 fp8 e4m3 (one u32) -> 4 floats (HW cvt)
__device__ __forceinline__ void unpf8(unsigned int w, float* f){
  f32x2_t lo = __builtin_amdgcn_cvt_pk_f32_fp8(w, false);
  f32x2_t hi = __builtin_amdgcn_cvt_pk_f32_fp8(w, true);
  f[0] = lo[0]; f[1] = lo[1]; f[2] = hi[0]; f[3] = hi[1];
}

#define GLOAD16(gsrc, ldst) \
  __builtin_amdgcn_global_load_lds((const __attribute__((address_space(1))) unsigned int*)(gsrc), \
                                   (__attribute__((address_space(3))) unsigned int*)(ldst), 16, 0, 0)

// ---------------- K-1: zero scratch (runtime's tiny-fill path is 41us; this is ~2us)
__global__ void zero_buf(uint4* __restrict__ p, int n16){
  int i = blockIdx.x * 256 + threadIdx.x;
  if (i < n16) p[i] = make_uint4(0, 0, 0, 0);
}

// ---------------- K0: fused prep — pack_weights | pack_wa1 | convert_x | degree_hist
__global__ void prep(const float* __restrict__ x,
                     const float* __restrict__ Wq, const float* __restrict__ Wk,
                     const float* __restrict__ Wv, const float* __restrict__ Ws,
                     const float* __restrict__ bq, const float* __restrict__ bk,
                     const float* __restrict__ bv, const float* __restrict__ bs,
                     const float* __restrict__ Wa1, const int* __restrict__ ei,
                     unsigned short* __restrict__ xbf, unsigned short* __restrict__ wcatT,
                     float* __restrict__ bcat, unsigned short* __restrict__ wa1T,
                     int* __restrict__ deg, int n, int ne, int nbcv){
  const int b = blockIdx.x, tid = threadIdx.x;
  if (b < 2048){
    int idx = b * 256 + tid;
    int c = idx >> 9, k = idx & 511;
    int sel = c >> 8, cc = c & 255;
    const float* W = (sel == 0) ? Wq : (sel == 1) ? Wk : (sel == 2) ? Wv : Ws;
    int p = ((k >> 3) & 3) ^ swz4(c & 127);
    int dst = c * 512 + (k & ~31) + p * 8 + (k & 7);
    wcatT[dst] = f2bf(W[k * 256 + cc]);
    if (idx < 1024){
      int sel2 = idx >> 8, cc2 = idx & 255;
      const float* B = (sel2 == 0) ? bq : (sel2 == 1) ? bk : (sel2 == 2) ? bv : bs;
      bcat[idx] = B[cc2];
    }
  } else if (b < 2304){
    int idx = (b - 2048) * 256 + tid;
    int c = idx >> 8, k = idx & 255;
    wa1T[idx] = f2bf(Wa1[k * 256 + c]);
  } else if (b < 2304 + nbcv){
    int idx = (b - 2304) * 256 + tid;
    if (idx < n * 64){
      int node = idx >> 6, un = idx & 63;
      int k0 = (un >> 2) * 32, u = un & 3;
      const float* src = x + (size_t)node * 512 + k0 + u * 8;
      float4 f0 = *reinterpret_cast<const float4*>(src);
      float4 f1 = *reinterpret_cast<const float4*>(src + 4);
      uint4 o;
      o.x = pk2bf(f0.x, f0.y); o.y = pk2bf(f0.z, f0.w);
      o.z = pk2bf(f1.x, f1.y); o.w = pk2bf(f1.z, f1.w);
      int p = u ^ swz4(node & 127);
      *reinterpret_cast<uint4*>(xbf + (size_t)node * 512 + k0 + p * 8) = o;
    }
  } else {
    int i = (b - 2304 - nbcv) * 256 + tid;
    if (i < ne) atomicAdd(&deg[ei[ne + i]], 1);
  }
}

// ---------------- K3: QKVS GEMM: triple-buffered async gload_lds (pre-swizzled images),
// counted vmcnt(8) + raw barriers, XCD-swizzled grid, swapped-operand MFMA,
// bank-uniform LDS-staged epilogue. Writes q/s bf16 + k/v fp8.
__global__ __launch_bounds__(256) void gemm_qkvs(const unsigned short* __restrict__ xbf,
                                                 const unsigned short* __restrict__ wcatT,
                                                 const float* __restrict__ bcat,
                                                 unsigned short* __restrict__ qbf,
                                                 unsigned short* __restrict__ sbf,
                                                 unsigned char* __restrict__ kv8,
                                                 int n_nodes, int mblocks){
  __shared__ __align__(16) unsigned char smem[49152];
  const int tid = threadIdx.x;
  const int lane = tid & 63, wave = tid >> 6;
  const int wm = wave >> 1, wn = wave & 1;
  const int g = (blockIdx.x & 7) * mblocks + (blockIdx.x >> 3);
  const int m_blk = g >> 3, n_blk = g & 7;
  const int m0 = m_blk * 128, n0 = n_blk * 128;
  const int lrow = lane >> 2;
  const int lcol = (lane & 3) * 8;
  const int rA0 = min(m0 + wave * 16 + lrow, n_nodes - 1);
  const int rA1 = min(m0 + (wave + 4) * 16 + lrow, n_nodes - 1);
  const int rB0 = n0 + wave * 16 + lrow;
  const int rB1 = rB0 + 64;
  const int r = lane & 15, q4 = lane >> 4;
  const unsigned short* aG0 = xbf   + (size_t)rA0 * 512 + lcol;
  const unsigned short* aG1 = xbf   + (size_t)rA1 * 512 + lcol;
  const unsigned short* bG0 = wcatT + (size_t)rB0 * 512 + lcol;
  const unsigned short* bG1 = wcatT + (size_t)rB1 * 512 + lcol;
  int aoff[4], boff[4];
  #pragma unroll
  for (int mi = 0; mi < 4; mi++){ int rr = wm * 64 + mi * 16 + r; aoff[mi] = rr * 32 + ((q4 ^ swz4(rr)) * 8); }
  #pragma unroll
  for (int ni = 0; ni < 4; ni++){ int rb = wn * 64 + ni * 16 + r; boff[ni] = rb * 32 + ((q4 ^ swz4(rb)) * 8); }
  f32x4_t acc[4][4] = {};
#define STAGE(base, k0) { \
    unsigned short* As_ = (unsigned short*)(smem + (base)); \
    unsigned short* Bs_ = (unsigned short*)(smem + (base) + 8192); \
    GLOAD16(aG0 + (k0), &As_[wave * 512]); \
    GLOAD16(aG1 + (k0), &As_[(wave + 4) * 512]); \
    GLOAD16(bG0 + (k0), &Bs_[wave * 512]); \
    GLOAD16(bG1 + (k0), &Bs_[(wave + 4) * 512]); \
  }
  STAGE(0, 0);
  STAGE(16384, 32);
  int cbase = 0;
  int sbase = 32768;
  for (int t = 0; t < 16; t++){
    if (t + 2 < 16){
      STAGE(sbase, (t + 2) * 32);
      asm volatile("s_waitcnt vmcnt(8)" ::: "memory");
    } else if (t + 1 < 16){
      asm volatile("s_waitcnt vmcnt(4)" ::: "memory");
    } else {
      asm volatile("s_waitcnt vmcnt(0)" ::: "memory");
    }
    __builtin_amdgcn_s_barrier();
    asm volatile("" ::: "memory");
    const unsigned short* As = (const unsigned short*)(smem + cbase);
    const unsigned short* Bs = (const unsigned short*)(smem + cbase + 8192);
    bf16x8_t a[4], b[4];
    #pragma unroll
    for (int mi = 0; mi < 4; mi++) a[mi] = *reinterpret_cast<const bf16x8_t*>(&As[aoff[mi]]);
    #pragma unroll
    for (int ni = 0; ni < 4; ni++) b[ni] = *reinterpret_cast<const bf16x8_t*>(&Bs[boff[ni]]);
    #pragma unroll
    for (int mi = 0; mi < 4; mi++)
      #pragma unroll
      for (int ni = 0; ni < 4; ni++)
        acc[mi][ni] = __builtin_amdgcn_mfma_f32_16x16x32_bf16(b[ni], a[mi], acc[mi][ni], 0, 0, 0);
    __builtin_amdgcn_s_barrier();
    asm volatile("" ::: "memory");
    cbase += 16384; if (cbase == 49152) cbase = 0;
    sbase += 16384; if (sbase == 49152) sbase = 0;
  }
#undef STAGE
  const bool isQ = (n_blk < 2), isS = (n_blk >= 6);
  if (isQ || isS){
    unsigned short* St = (unsigned short*)smem;   // [64][152] bf16
    unsigned short* outp = isQ ? qbf : sbf;
    const int colhalf = isQ ? n_blk : (n_blk - 6);
    #pragma unroll
    for (int ch = 0; ch < 2; ch++){
      if (wm == ch){
        #pragma unroll
        for (int mi = 0; mi < 4; mi++){
          #pragma unroll
          for (int ni = 0; ni < 4; ni++){
            int mloc = mi * 16 + r;
            int nl = wn * 64 + ni * 16 + q4 * 4;
            float4 bb = *reinterpret_cast<const float4*>(&bcat[n0 + nl]);
            uint2 w;
            w.x = pk2bf(acc[mi][ni][0] + bb.x, acc[mi][ni][1] + bb.y);
            w.y = pk2bf(acc[mi][ni][2] + bb.z, acc[mi][ni][3] + bb.w);
            *reinterpret_cast<uint2*>(&St[mloc * 152 + nl]) = w;
          }
        }
      }
      __syncthreads();
      #pragma unroll
      for (int it = 0; it < 4; it++){
        int u = it * 256 + tid;
        int row = u >> 4, seg = (u & 15) * 8;
        int node = m0 + ch * 64 + row;
        if (node < n_nodes){
          uint4 v = *reinterpret_cast<const uint4*>(&St[row * 152 + seg]);
          *reinterpret_cast<uint4*>(outp + (size_t)node * 256 + colhalf * 128 + seg) = v;
        }
      }
      __syncthreads();
    }
  } else {
    unsigned char* St8 = smem;                    // [64][144] fp8
    #pragma unroll
    for (int ch = 0; ch < 2; ch++){
      if (wm == ch){
        #pragma unroll
        for (int mi = 0; mi < 4; mi++){
          #pragma unroll
          for (int ni = 0; ni < 4; ni++){
            int mloc = mi * 16 + r;
            int nl = wn * 64 + ni * 16 + q4 * 4;
            float4 bb = *reinterpret_cast<const float4*>(&bcat[n0 + nl]);
            int u = 0;
            u = __builtin_amdgcn_cvt_pk_fp8_f32(acc[mi][ni][0] + bb.x, acc[mi][ni][1] + bb.y, u, false);
            u = __builtin_amdgcn_cvt_pk_fp8_f32(acc[mi][ni][2] + bb.z, acc[mi][ni][3] + bb.w, u, true);
            *reinterpret_cast<unsigned int*>(&St8[mloc * 144 + nl]) = (unsigned int)u;
          }
        }
      }
      __syncthreads();
      #pragma unroll
      for (int it = 0; it < 2; it++){
        int u = it * 256 + tid;
        int row = u >> 3, seg = (u & 7) * 16;
        int node = m0 + ch * 64 + row;
        if (node < n_nodes){
          uint4 v = *reinterpret_cast<const uint4*>(&St8[row * 144 + seg]);
          *reinterpret_cast<uint4*>(kv8 + (size_t)node * 512 + (n_blk - 2) * 128 + seg) = v;
        }
      }
      __syncthreads();
    }
  }
}

// ---------------- K5: exclusive scan, single block, 2-pass blocked
__global__ void scan_deg(const int* __restrict__ deg, int* __restrict__ rowstart, int n, int ne){
  __shared__ int sm[1024];
  int tid = threadIdx.x;
  int per = (n + 1023) / 1024;
  int start = tid * per;
  int sum = 0;
  for (int i = 0; i < per; i++){
    int idx = start + i;
    sum += (idx < n) ? deg[idx] : 0;
  }
  sm[tid] = sum; __syncthreads();
  for (int off = 1; off < 1024; off <<= 1){
    int t = (tid >= off) ? sm[tid - off] : 0;
    __syncthreads();
    sm[tid] += t;
    __syncthreads();
  }
  int run = sm[tid] - sum;
  for (int i = 0; i < per; i++){
    int idx = start + i;
    if (idx < n){
      rowstart[idx] = run;
      run += deg[idx];
    }
  }
  if (tid == 0) rowstart[n] = ne;
}

// ---------------- K6: scatter edges into CSR (stores src*512 byte-offset)
__global__ void scatter_edges(const int* __restrict__ ei, const int* __restrict__ rowstart,
                              int* __restrict__ cursor, int* __restrict__ csrsrc, int ne){
  int i = blockIdx.x * 256 + threadIdx.x;
  if (i < ne){
    int d = ei[ne + i];
    int pos = atomicAdd(&cursor[d], 1);
    csrsrc[rowstart[d] + pos] = ei[i] << 9;
  }
}

// ---------------- K7: per-dst online-softmax aggregation
// fp8 K/V, 16 lanes/edge, 2 chains/node (2x16-lane groups, stride-2 edges), 2 nodes/wave,
// pair-processing + pair prefetch within each chain, shfl_xor(16) chain merge.
__global__ __launch_bounds__(256) void edge_attn(const unsigned short* __restrict__ qbf,
                                                 const unsigned short* __restrict__ sbf,
                                                 const unsigned char* __restrict__ kv8,
                                                 const int* __restrict__ rowstart,
                                                 const int* __restrict__ csrsrc,
                                                 unsigned short* __restrict__ hbf, int n_nodes){
  const int tid = threadIdx.x;
  const int lane = tid & 63, wave = tid >> 6;
  const int g = lane >> 4, t = lane & 15;
  const int chain = g & 1;
  const int node = blockIdx.x * 8 + wave * 2 + (g >> 1);
  const bool active = node < n_nodes;
  const int nd = active ? node : 0;
  const float qs = 0.0625f * 1.44269504088896340736f;  // (1/sqrt(256)) * log2(e)
  float q[16];
  {
    const unsigned short* qp = qbf + (size_t)nd * 256 + t * 16;
    uint4 w0 = *reinterpret_cast<const uint4*>(qp);
    uint4 w1 = *reinterpret_cast<const uint4*>(qp + 8);
    unp8s(w0, q, qs); unp8s(w1, q + 8, qs);
  }
  int rs = rowstart[nd];
  int re = active ? rowstart[nd + 1] : rs;
  float m = -1e30f, den = 0.f;
  float acc[16];
  #pragma unroll
  for (int j = 0; j < 16; j++) acc[j] = 0.f;
  // this chain's edges: rs+chain, rs+chain+2, ... (stride 2); pair = (i, i+2), step 4
  const int i0 = rs + chain;
  uint4 kA = make_uint4(0,0,0,0), vA = kA, kB = kA, vB = kA;
  if (i0 < re){
    const unsigned char* p1 = kv8 + (size_t)csrsrc[i0] + t * 16;
    kA = *reinterpret_cast<const uint4*>(p1);
    vA = *reinterpret_cast<const uint4*>(p1 + 256);
    if (i0 + 2 < re){
      const unsigned char* p2 = kv8 + (size_t)csrsrc[i0 + 2] + t * 16;
      kB = *reinterpret_cast<const uint4*>(p2);
      vB = *reinterpret_cast<const uint4*>(p2 + 256);
    }
  }
  for (int i = i0; i < re; i += 4){
    uint4 k1 = kA, v1 = vA, k2 = kB, v2 = vB;
    const bool has2 = (i + 2 < re);
    if (i + 4 < re){
      const unsigned char* p1 = kv8 + (size_t)csrsrc[i + 4] + t * 16;
      kA = *reinterpret_cast<const uint4*>(p1);
      vA = *reinterpret_cast<const uint4*>(p1 + 256);
      if (i + 6 < re){
        const unsigned char* p2 = kv8 + (size_t)csrsrc[i + 6] + t * 16;
        kB = *reinterpret_cast<const uint4*>(p2);
        vB = *reinterpret_cast<const uint4*>(p2 + 256);
      }
    }
    float kf1[16], kf2[16];
    unpf8(k1.x, kf1); unpf8(k1.y, kf1 + 4); unpf8(k1.z, kf1 + 8); unpf8(k1.w, kf1 + 12);
    unpf8(k2.x, kf2); unpf8(k2.y, kf2 + 4); unpf8(k2.z, kf2 + 8); unpf8(k2.w, kf2 + 12);
    float s1 = 0.f, s2 = 0.f;
    #pragma unroll
    for (int j = 0; j < 16; j++){ s1 = fmaf(q[j], kf1[j], s1); s2 = fmaf(q[j], kf2[j], s2); }
    s1 += __shfl_xor(s1, 1); s2 += __shfl_xor(s2, 1);
    s1 += __shfl_xor(s1, 2); s2 += __shfl_xor(s2, 2);
    s1 += __shfl_xor(s1, 4); s2 += __shfl_xor(s2, 4);
    s1 += __shfl_xor(s1, 8); s2 += __shfl_xor(s2, 8);
    if (!has2) s2 = -1e30f;
    float vf1[16], vf2[16];
    unpf8(v1.x, vf1); unpf8(v1.y, vf1 + 4); unpf8(v1.z, vf1 + 8); unpf8(v1.w, vf1 + 12);
    unpf8(v2.x, vf2); unpf8(v2.y, vf2 + 4); unpf8(v2.z, vf2 + 8); unpf8(v2.w, vf2 + 12);
    float mn = fmaxf(m, fmaxf(s1, s2));
    float sc = exp2f(m - mn);
    float e1 = exp2f(s1 - mn);
    float e2 = exp2f(s2 - mn);
    den = den * sc + e1 + e2;
    #pragma unroll
    for (int j = 0; j < 16; j++)
      acc[j] = fmaf(acc[j], sc, fmaf(e1, vf1[j], e2 * vf2[j]));
    m = mn;
  }
  // merge the two chains (lane ^ 16 pairs groups 0<->1, 2<->3)
  {
    float mo  = __shfl_xor(m, 16);
    float dno = __shfl_xor(den, 16);
    float mn  = fmaxf(m, mo);
    float a_  = exp2f(m - mn);
    float b_  = exp2f(mo - mn);
    den = den * a_ + dno * b_;
    #pragma unroll
    for (int j = 0; j < 16; j++){
      float oth = __shfl_xor(acc[j], 16);
      acc[j] = acc[j] * a_ + oth * b_;
    }
  }
  float inv = (den > 0.f) ? 1.f / den : 0.f;
  const unsigned short* sp = sbf + (size_t)nd * 256 + t * 16;
  uint4 s0 = *reinterpret_cast<const uint4*>(sp);
  uint4 s1v = *reinterpret_cast<const uint4*>(sp + 8);
  float sf[16]; unp8s(s0, sf, 1.0f); unp8s(s1v, sf + 8, 1.0f);
  const float inv_sqrt2 = 0.70710678118654752f;
  unsigned int o[8];
  #pragma unroll
  for (int j = 0; j < 8; j++){
    float h0 = acc[2 * j] * inv + sf[2 * j];
    float h1 = acc[2 * j + 1] * inv + sf[2 * j + 1];
    h0 = 0.5f * h0 * (1.f + erff(h0 * inv_sqrt2));
    h1 = 0.5f * h1 * (1.f + erff(h1 * inv_sqrt2));
    o[j] = (unsigned int)f2bf(h0) | ((unsigned int)f2bf(h1) << 16);
  }
  if (active && chain == 0){
    uint4* dst = reinterpret_cast<uint4*>(hbf + (size_t)node * 256 + t * 16);
    dst[0] = make_uint4(o[0], o[1], o[2], o[3]);
    dst[1] = make_uint4(o[4], o[5], o[6], o[7]);
  }
}

// ---------------- K8: s2[n][2] = tanh(hbf@Wa1 + ba1)@Wa2 + ba2  (bf16 MFMA)
__global__ __launch_bounds__(256) void mlp_mfma(const unsigned short* __restrict__ hbf,
                                                const unsigned short* __restrict__ wa1T,
                                                const float* __restrict__ ba1,
                                                const float* __restrict__ Wa2,
                                                const float* __restrict__ ba2,
                                                float* __restrict__ s2, int n_nodes){
  __shared__ __align__(16) unsigned short As[64 * 72];
  __shared__ float s2s[64][2];
  const int tid = threadIdx.x;
  const int lane = tid & 63, wave = tid >> 6;
  const int m0 = blockIdx.x * 64;
  const int c0 = wave * 64;
  const int r = lane & 15, rg = (lane >> 4) * 4;
  if (tid < 128) s2s[tid >> 1][tid & 1] = 0.f;
  f32x4_t acc[4][4] = {};
  for (int k0 = 0; k0 < 256; k0 += 64){
    int arow = tid >> 2, akc = (tid & 3) * 16;
    uint4 a0v = make_uint4(0,0,0,0), a1v = make_uint4(0,0,0,0);
    if (m0 + arow < n_nodes){
      const unsigned short* src = hbf + (size_t)(m0 + arow) * 256 + k0 + akc;
      a0v = *reinterpret_cast<const uint4*>(src);
      a1v = *reinterpret_cast<const uint4*>(src + 8);
    }
    *reinterpret_cast<uint4*>(&As[arow * 72 + akc]) = a0v;
    *reinterpret_cast<uint4*>(&As[arow * 72 + akc + 8]) = a1v;
    __syncthreads();
    #pragma unroll
    for (int kk = 0; kk < 2; kk++){
      int kg = kk * 32 + (lane >> 4) * 8;
      bf16x8_t a[4], b[4];
      #pragma unroll
      for (int mi = 0; mi < 4; mi++)
        a[mi] = *reinterpret_cast<const bf16x8_t*>(&As[(mi * 16 + r) * 72 + kg]);
      #pragma unroll
      for (int ni = 0; ni < 4; ni++)
        b[ni] = *reinterpret_cast<const bf16x8_t*>(wa1T + (size_t)(c0 + ni * 16 + r) * 256 + k0 + kg);
      #pragma unroll
      for (int mi = 0; mi < 4; mi++)
        #pragma unroll
        for (int ni = 0; ni < 4; ni++)
          acc[mi][ni] = __builtin_amdgcn_mfma_f32_16x16x32_bf16(a[mi], b[ni], acc[mi][ni], 0, 0, 0);
    }
    __syncthreads();
  }
  float w20[4], w21[4], b1c[4];
  #pragma unroll
  for (int ni = 0; ni < 4; ni++){
    int col = c0 + ni * 16 + r;
    w20[ni] = Wa2[col * 2]; w21[ni] = Wa2[col * 2 + 1]; b1c[ni] = ba1[col];
  }
  #pragma unroll
  for (int mi = 0; mi < 4; mi++){
    #pragma unroll
    for (int j = 0; j < 4; j++){
      float t0 = 0.f, t1 = 0.f;
      #pragma unroll
      for (int ni = 0; ni < 4; ni++){
        float t = tanhf(acc[mi][ni][j] + b1c[ni]);
        t0 += t * w20[ni]; t1 += t * w21[ni];
      }
      t0 += __shfl_xor(t0, 1); t0 += __shfl_xor(t0, 2);
      t0 += __shfl_xor(t0, 4); t0 += __shfl_xor(t0, 8);
      t1 += __shfl_xor(t1, 1); t1 += __shfl_xor(t1, 2);
      t1 += __shfl_xor(t1, 4); t1 += __shfl_xor(t1, 8);
      if (r == 0){
        int row = mi * 16 + rg + j;
        atomicAdd(&s2s[row][0], t0);
        atomicAdd(&s2s[row][1], t1);
      }
    }
  }
  __syncthreads();
  if (tid < 128){
    int row = tid >> 1, c = tid & 1;
    int node = m0 + row;
    if (node < n_nodes) s2[node * 2 + c] = s2s[row][c] + ba2[c];
  }
}

// ---------------- K9: column max + exp-sum over n (single block)
__global__ void col_reduce(const float* __restrict__ s2, float* __restrict__ red, int n){
  __shared__ float sm[1024];
  __shared__ float mshare[2];
  int tid = threadIdx.x;
  float mx0 = -INFINITY, mx1 = -INFINITY;
  for (int i = tid; i < n; i += 1024){
    mx0 = fmaxf(mx0, s2[2 * i]);
    mx1 = fmaxf(mx1, s2[2 * i + 1]);
  }
  sm[tid] = mx0; __syncthreads();
  for (int off = 512; off > 0; off >>= 1){
    if (tid < off) sm[tid] = fmaxf(sm[tid], sm[tid + off]);
    __syncthreads();
  }
  if (tid == 0) mshare[0] = sm[0];
  __syncthreads();
  sm[tid] = mx1; __syncthreads();
  for (int off = 512; off > 0; off >>= 1){
    if (tid < off) sm[tid] = fmaxf(sm[tid], sm[tid + off]);
    __syncthreads();
  }
  if (tid == 0) mshare[1] = sm[0];
  __syncthreads();
  float m0 = mshare[0], m1 = mshare[1];
  float s0 = 0.f, s1 = 0.f;
  for (int i = tid; i < n; i += 1024){
    s0 += expf(s2[2 * i] - m0);
    s1 += expf(s2[2 * i + 1] - m1);
  }
  sm[tid] = s0; __syncthreads();
  for (int off = 512; off > 0; off >>= 1){
    if (tid < off) sm[tid] += sm[tid + off];
    __syncthreads();
  }
  float den0 = sm[0];
  __syncthreads();
  sm[tid] = s1; __syncthreads();
  for (int off = 512; off > 0; off >>= 1){
    if (tid < off) sm[tid] += sm[tid + off];
    __syncthreads();
  }
  if (tid == 0){
    red[0] = m0; red[1] = m1; red[2] = den0; red[3] = sm[0];
  }
}

// ---------------- K10: attn, A output, M partial accumulation (reads bf16 h)
__global__ __launch_bounds__(256) void attn_M(const float* __restrict__ s2, const float* __restrict__ red,
                                              const unsigned short* __restrict__ hbf, const int* __restrict__ label,
                                              float* __restrict__ Mbuf, float* __restrict__ outA, int n){
  __shared__ float a0s[256], a1s[256];
  int tid = threadIdx.x;
  int n0 = blockIdx.x * 256;
  int node = n0 + tid;
  float m0 = red[0], m1 = red[1];
  float i0 = 1.f / red[2], i1 = 1.f / red[3];
  float a0 = 0.f, a1 = 0.f;
  if (node < n){
    a0 = expf(s2[2 * node] - m0) * i0;
    a1 = expf(s2[2 * node + 1] - m1) * i1;
    outA[node] = (label[0] == 0) ? a0 : a1;
  }
  a0s[tid] = a0; a1s[tid] = a1;
  __syncthreads();
  int d = tid;
  float M0 = 0.f, M1 = 0.f;
  int cnt = min(256, n - n0);
  for (int i = 0; i < cnt; i++){
    float hv = bf2f((unsigned int)hbf[(size_t)(n0 + i) * 256 + d]);
    M0 += a0s[i] * hv;
    M1 += a1s[i] * hv;
  }
  atomicAdd(&Mbuf[d], M0);
  atomicAdd(&Mbuf[256 + d], M1);
}

// ---------------- K11: logits + Y_prob
__global__ void final_k(const float* __restrict__ Mbuf, const float* __restrict__ Wc,
                        const float* __restrict__ bc, float* __restrict__ out){
  __shared__ float sm[256];
  __shared__ float l0s;
  int tid = threadIdx.x;
  float p0 = Mbuf[tid] * Wc[tid];
  float p1 = Mbuf[256 + tid] * Wc[256 + tid];
  sm[tid] = p0; __syncthreads();
  for (int off = 128; off > 0; off >>= 1){
    if (tid < off) sm[tid] += sm[tid + off];
    __syncthreads();
  }
  if (tid == 0) l0s = sm[0];
  __syncthreads();
  sm[tid] = p1; __syncthreads();
  for (int off = 128; off > 0; off >>= 1){
    if (tid < off) sm[tid] += sm[tid + off];
    __syncthreads();
  }
  if (tid == 0){
    float l0 = l0s + bc[0];
    float l1 = sm[0] + bc[1];
    out[0] = l0; out[1] = l1;
    float mx = fmaxf(l0, l1);
    float e0 = expf(l0 - mx), e1 = expf(l1 - mx);
    float inv = 1.f / (e0 + e1);
    out[2] = e0 * inv; out[3] = e1 * inv;
  }
}

extern "C" void kernel_launch(void* const* d_in, const int* in_sizes, int n_in,
                              void* d_out, int out_size, void* d_ws, size_t ws_size,
                              hipStream_t stream) {
  const float* x   = (const float*)d_in[0];
  const int*   ei  = (const int*)d_in[1];
  const int*   lab = (const int*)d_in[2];
  const float* Wq  = (const float*)d_in[3];
  const float* bq  = (const float*)d_in[4];
  const float* Wk  = (const float*)d_in[5];
  const float* bk  = (const float*)d_in[6];
  const float* Wv  = (const float*)d_in[7];
  const float* bv  = (const float*)d_in[8];
  const float* Ws  = (const float*)d_in[9];
  const float* bs  = (const float*)d_in[10];
  const float* Wa1 = (const float*)d_in[11];
  const float* ba1 = (const float*)d_in[12];
  const float* Wa2 = (const float*)d_in[13];
  const float* ba2 = (const float*)d_in[14];
  const float* Wc  = (const float*)d_in[15];
  const float* bc  = (const float*)d_in[16];
  float* out = (float*)d_out;

  const int n  = in_sizes[0] / 512;   // 20000
  const int ne = in_sizes[1] / 2;     // 320000

  char* ws = (char*)d_ws;
  size_t off = 0;
  auto take = [&](size_t bytes){ size_t r = off; off += (bytes + 255) & ~(size_t)255; return r; };
  unsigned short* wcatT  = (unsigned short*)(ws + take((size_t)1024 * 512 * 2));
  float*          bcat   = (float*)(ws + take(1024 * 4));
  unsigned short* xbf    = (unsigned short*)(ws + take((size_t)n * 512 * 2));
  unsigned short* qbf    = (unsigned short*)(ws + take((size_t)n * 256 * 2));
  unsigned short* sbf    = (unsigned short*)(ws + take((size_t)n * 256 * 2));
  unsigned char*  kv8    = (unsigned char*)(ws + take((size_t)n * 512));
  unsigned short* hbf    = (unsigned short*)(ws + take((size_t)n * 256 * 2));
  unsigned short* wa1T   = (unsigned short*)(ws + take((size_t)256 * 256 * 2));
  float*          s2     = (float*)(ws + take((size_t)n * 2 * 4));
  size_t zoff = off;
  int*            deg    = (int*)(ws + take((size_t)n * 4));
  int*            cursor = (int*)(ws + take((size_t)n * 4));
  float*          Mbuf   = (float*)(ws + take(512 * 4));
  size_t zlen = off - zoff;
  int*            rowst  = (int*)(ws + take((size_t)(n + 1) * 4));
  int*            csrsrc = (int*)(ws + take((size_t)ne * 4));
  float*          red    = (float*)(ws + take(4 * 4));

  const int z16 = (int)(zlen / 16);
  zero_buf<<<(z16 + 255) / 256, 256, 0, stream>>>((uint4*)(ws + zoff), z16);

  const int nbcv = (n * 64 + 255) / 256;
  const int nbdh = (ne + 255) / 256;
  prep<<<2304 + nbcv + nbdh, 256, 0, stream>>>(x, Wq, Wk, Wv, Ws, bq, bk, bv, bs, Wa1, ei,
                                               xbf, wcatT, bcat, wa1T, deg, n, ne, nbcv);
  const int mblocks = (n + 127) / 128;
  gemm_qkvs<<<8 * mblocks, 256, 0, stream>>>(xbf, wcatT, bcat, qbf, sbf, kv8, n, mblocks);
  scan_deg<<<1, 1024, 0, stream>>>(deg, rowst, n, ne);
  scatter_edges<<<(ne + 255) / 256, 256, 0, stream>>>(ei, rowst, cursor, csrsrc, ne);
  edge_attn<<<(n + 7) / 8, 256, 0, stream>>>(qbf, sbf, kv8, rowst, csrsrc, hbf, n);
  mlp_mfma<<<(n + 63) / 64, 256, 0, stream>>>(hbf, wa1T, ba1, Wa2, ba2, s2, n);
  col_reduce<<<1, 1024, 0, stream>>>(s2, red, n);
  attn_M<<<(n + 255) / 256, 256, 0, stream>>>(s2, red, hbf, lab, Mbuf, out + 4, n);
  final_k<<<1, 256, 0, stream>>>(Mbuf, Wc, bc, out);
  (void)ws_size; (void)out_size; (void)n_in;
}